// Round 11
// baseline (861.078 us; speedup 1.0000x reference)
//
#include <hip/hip_runtime.h>
#include <stdint.h>

typedef __bf16 bf16x8 __attribute__((ext_vector_type(8)));
typedef float f32x4 __attribute__((ext_vector_type(4)));
typedef unsigned short ushort8 __attribute__((ext_vector_type(8)));

__device__ __forceinline__ float bf2f(unsigned short u) {
  union { uint32_t i; float f; } v; v.i = ((uint32_t)u) << 16; return v.f;
}
__device__ __forceinline__ unsigned short f2bf(float f) {
  union { uint32_t i; float f; } v; v.f = f;
  uint32_t u = v.i;
  return (unsigned short)((u + 0x7fffu + ((u >> 16) & 1u)) >> 16);
}
__device__ __forceinline__ float sigm(float x) { return 1.0f / (1.0f + __expf(-x)); }
__device__ __forceinline__ float tanh_f(float x) { return 1.0f - 2.0f / (__expf(2.0f * x) + 1.0f); }

__device__ __forceinline__ ushort4 cvt4(float4 a) {
  ushort4 o; o.x = f2bf(a.x); o.y = f2bf(a.y); o.z = f2bf(a.z); o.w = f2bf(a.w); return o;
}

// bijective XCD-aware remap (m204)
__device__ __forceinline__ int xcd_swz(int bid, int nwg) {
  int q = nwg >> 3, r = nwg & 7;
  int x = bid & 7, idx = bid >> 3;
  return (x < r ? x * (q + 1) : r * (q + 1) + (x - r) * q) + idx;
}

// ---------- fp32 -> bf16 bulk convert ----------
__global__ void k_f2bf(const float* __restrict__ src, unsigned short* __restrict__ dst, long long n8) {
  long long t = (long long)blockIdx.x * blockDim.x + threadIdx.x;
  if (t >= n8) return;
  const float4* s = (const float4*)src + t * 2;
  float4 a = s[0], b = s[1];
  ((ushort4*)dst)[t * 2]     = cvt4(a);
  ((ushort4*)dst)[t * 2 + 1] = cvt4(b);
}

// ---------- degree histogram ----------
__global__ void k_hist(const int* __restrict__ parent, int* __restrict__ deg, int M) {
  int e = blockIdx.x * blockDim.x + threadIdx.x;
  if (e < M) atomicAdd(&deg[parent[e]], 1);
}

// ---------- packed scan pass 1 ----------
__global__ void k_scan1(const int* __restrict__ deg, unsigned long long* __restrict__ ps,
                        unsigned long long* __restrict__ bsum, int Nn) {
  __shared__ unsigned long long tmp[256];
  int t = blockIdx.x * 256 + threadIdx.x;
  int d = (t < Nn) ? deg[t] : 0;
  unsigned long long v = (unsigned long long)(unsigned)d | ((d > 0) ? (1ull << 32) : 0ull);
  tmp[threadIdx.x] = v;
  __syncthreads();
#pragma unroll
  for (int s = 1; s < 256; s <<= 1) {
    unsigned long long a = (threadIdx.x >= (unsigned)s) ? tmp[threadIdx.x - s] : 0;
    __syncthreads();
    tmp[threadIdx.x] += a;
    __syncthreads();
  }
  if (t < Nn) ps[t] = tmp[threadIdx.x] - v;
  if (threadIdx.x == 255) bsum[blockIdx.x] = tmp[255];
}

// ---------- scan pass 2 + meta (L0 256-aligned for 256-row panels) ----------
__global__ void k_scan2(unsigned long long* __restrict__ bsum, int nb,
                        int* __restrict__ meta, int Nn) {
  __shared__ unsigned long long tmp[512];
  int i = threadIdx.x;
  unsigned long long v = (i < nb) ? bsum[i] : 0;
  tmp[i] = v;
  __syncthreads();
#pragma unroll
  for (int s = 1; s < 512; s <<= 1) {
    unsigned long long a = (i >= s) ? tmp[i - s] : 0;
    __syncthreads();
    tmp[i] += a;
    __syncthreads();
  }
  if (i < nb) bsum[i] = tmp[i] - v;
  if (i == 511) {
    int Ni = (int)(tmp[511] >> 32);
    int L0 = ((Ni + 255) >> 8) << 8;   // 256-aligned leaf base
    meta[0] = Ni;
    meta[1] = L0;
    meta[2] = L0 + (Nn - Ni);
  }
}

// ---------- scan pass 3: rs/cursor + slot + nodeof ----------
__global__ void k_scan3(const unsigned long long* __restrict__ ps,
                        const unsigned long long* __restrict__ bsum,
                        const int* __restrict__ meta, const int* __restrict__ deg,
                        int* __restrict__ rs, int* __restrict__ cursor,
                        int* __restrict__ slot, int* __restrict__ nodeof, int Nn) {
  int t = blockIdx.x * 256 + threadIdx.x;
  if (t >= Nn) return;
  unsigned long long p = ps[t] + bsum[blockIdx.x];
  int r  = (int)(p & 0xffffffffull);
  int si = (int)(p >> 32);
  rs[t] = r;
  cursor[t] = r;
  int sl = (deg[t] > 0) ? si : (meta[1] + (t - si));
  slot[t] = sl;
  nodeof[sl] = t;
}

// ---------- bucket edges by parent ----------
__global__ void k_fill(const int* __restrict__ parent, const int* __restrict__ child,
                       int* __restrict__ cursor, int* __restrict__ childlist, int M) {
  int e = blockIdx.x * blockDim.x + threadIdx.x;
  if (e >= M) return;
  int p = parent[e];
  int pos = atomicAdd(&cursor[p], 1);
  childlist[pos] = child[e];
}

// ---------- gather-reduce: Zp[slot]=bf16(sum h_ch | x); credb[slot]=bf16(sum fc_ch) ----------
__global__ void k_reduce(const unsigned short* __restrict__ hbuf,
                         const unsigned short* __restrict__ fcb, const float* __restrict__ x,
                         const int* __restrict__ rs, const int* __restrict__ childlist,
                         const int* __restrict__ slot,
                         unsigned short* __restrict__ Zp, unsigned short* __restrict__ credb,
                         int Nn, int M) {
  int p = blockIdx.x * 4 + (threadIdx.x >> 6);
  if (p >= Nn) return;
  int ln = threadIdx.x & 63;
  int j = ln * 8;
  int start = rs[p];
  int end = (p + 1 < Nn) ? rs[p + 1] : M;
  size_t zb = (size_t)slot[p] * 512 + j;
  if (end > start) {
    float hs[8] = {0, 0, 0, 0, 0, 0, 0, 0};
    float cs[8] = {0, 0, 0, 0, 0, 0, 0, 0};
    for (int i = start; i < end; ++i) {
      int ch = childlist[i];
      size_t cb = (size_t)ch * 512 + j;
      ushort8 hv = *(const ushort8*)(hbuf + cb);
      ushort8 fv = *(const ushort8*)(fcb + cb);
#pragma unroll
      for (int q = 0; q < 8; ++q) {
        hs[q] += bf2f(hv[q]);
        cs[q] += bf2f(fv[q]);
      }
    }
    float4 h0 = {hs[0], hs[1], hs[2], hs[3]}, h1 = {hs[4], hs[5], hs[6], hs[7]};
    float4 c0 = {cs[0], cs[1], cs[2], cs[3]}, c1 = {cs[4], cs[5], cs[6], cs[7]};
    ((ushort4*)(Zp + zb))[0] = cvt4(h0);
    ((ushort4*)(Zp + zb))[1] = cvt4(h1);
    ((ushort4*)(credb + zb))[0] = cvt4(c0);   // slot-order: coalesced read in fused GEMM
    ((ushort4*)(credb + zb))[1] = cvt4(c1);
  } else {
    const float4* s = (const float4*)(x + (size_t)p * 512 + j);
    float4 x0 = s[0], x1 = s[1];
    ((ushort4*)(Zp + zb))[0] = cvt4(x0);
    ((ushort4*)(Zp + zb))[1] = cvt4(x1);
  }
}

// ---------- f-gate GEMM: 256x128 tile, 8 waves, counted-vmcnt dbuf pipeline + T2 swizzle ----------
// fc = sigmoid(hbuf @ Wf^T + b) * c
__global__ __launch_bounds__(512)
void k_gemm_f(const unsigned short* __restrict__ A,
              const unsigned short* __restrict__ Bt,
              const float* __restrict__ bias, const float* __restrict__ cmat,
              unsigned short* __restrict__ C, int Mrows) {
  __shared__ __align__(16) unsigned short ldsA[2][256 * 32];
  __shared__ __align__(16) unsigned short ldsB[2][128 * 32];
  const int K = 512, ldc = 512;
  const int tid = threadIdx.x;
  const int wv = tid >> 6, ln = tid & 63;
  const int wr = wv >> 1, wc = wv & 1;
  int wg = xcd_swz(blockIdx.x, gridDim.x);
  int rowp = wg >> 2;
  int colp = wg & 3;
  const int row0 = rowp * 256;
  const int col0 = colp * 128;

  f32x4 acc[4][4] = {};

  auto stage = [&](int buf, int k0) {   // exactly 3 global_load_lds per thread
#pragma unroll
    for (int rep = 0; rep < 2; ++rep) {
      int cidx = rep * 512 + tid;
      int r  = cidx >> 2;
      int kc = cidx & 3;
      int kp = (kc ^ ((r >> 1) & 3)) * 8;
      int ga = row0 + r; if (ga > Mrows - 1) ga = Mrows - 1;
      const unsigned short* srcA = A + (size_t)ga * K + k0 + kp;
      __builtin_amdgcn_global_load_lds(
          (const __attribute__((address_space(1))) void*)(void*)srcA,
          (__attribute__((address_space(3))) void*)(&ldsA[buf][(size_t)cidx * 8]),
          16, 0, 0);
    }
    {
      int cidx = tid;
      int r  = cidx >> 2;
      int kc = cidx & 3;
      int kp = (kc ^ ((r >> 1) & 3)) * 8;
      const unsigned short* srcB = Bt + (size_t)(col0 + r) * K + k0 + kp;
      __builtin_amdgcn_global_load_lds(
          (const __attribute__((address_space(1))) void*)(void*)srcB,
          (__attribute__((address_space(3))) void*)(&ldsB[buf][(size_t)cidx * 8]),
          16, 0, 0);
    }
  };

  const int kcr = ((ln >> 4) ^ ((ln >> 1) & 3)) * 8;
  auto compute = [&](int buf) {
    bf16x8 af[4], bfr[4];
#pragma unroll
    for (int mi = 0; mi < 4; ++mi)
      af[mi] = *(const bf16x8*)(&ldsA[buf][(size_t)(wr * 64 + mi * 16 + (ln & 15)) * 32 + kcr]);
#pragma unroll
    for (int ni = 0; ni < 4; ++ni)
      bfr[ni] = *(const bf16x8*)(&ldsB[buf][(size_t)(wc * 64 + ni * 16 + (ln & 15)) * 32 + kcr]);
#pragma unroll
    for (int mi = 0; mi < 4; ++mi)
#pragma unroll
      for (int ni = 0; ni < 4; ++ni)
        acc[mi][ni] = __builtin_amdgcn_mfma_f32_16x16x32_bf16(bfr[ni], af[mi], acc[mi][ni], 0, 0, 0);
  };

  stage(0, 0);
  int cur = 0;
#pragma unroll
  for (int kt = 0; kt < 15; ++kt) {
    stage(cur ^ 1, (kt + 1) * 32);
    asm volatile("s_waitcnt vmcnt(3)" ::: "memory");
    __builtin_amdgcn_s_barrier();
    compute(cur);
    __builtin_amdgcn_s_barrier();
    cur ^= 1;
  }
  asm volatile("s_waitcnt vmcnt(0)" ::: "memory");
  __builtin_amdgcn_s_barrier();
  compute(cur);

#pragma unroll
  for (int mi = 0; mi < 4; ++mi) {
    int gm = row0 + wr * 64 + mi * 16 + (ln & 15);
    if (gm >= Mrows) continue;
#pragma unroll
    for (int ni = 0; ni < 4; ++ni) {
      int gn = col0 + wc * 64 + ni * 16 + (ln >> 4) * 4;
      float4 bv = *(const float4*)(bias + gn);
      float4 cv = *(const float4*)(cmat + (size_t)gm * ldc + gn);
      ushort4 o;
      o.x = f2bf(sigm(acc[mi][ni][0] + bv.x) * cv.x);
      o.y = f2bf(sigm(acc[mi][ni][1] + bv.y) * cv.y);
      o.z = f2bf(sigm(acc[mi][ni][2] + bv.z) * cv.z);
      o.w = f2bf(sigm(acc[mi][ni][3] + bv.w) * cv.w);
      *(ushort4*)(C + (size_t)gm * ldc + gn) = o;
    }
  }
}

// ---------- fused iou GEMM + LSTM epilogue: 3 sequential gate passes ----------
// Gate order: pass 0 -> i (B rows 0..511), pass 1 -> u (rows 1024..1535),
// pass 2 -> o (rows 512..1023).  g = (2*p) % 3.
__global__ __launch_bounds__(512)
void k_gemm_iou_fused(const unsigned short* __restrict__ Zp,
                      const unsigned short* __restrict__ Ub,
                      const unsigned short* __restrict__ Wb,
                      const float* __restrict__ bias,
                      const int* __restrict__ meta,
                      const int* __restrict__ nodeof,
                      const unsigned short* __restrict__ credb,
                      float* __restrict__ out, int Nn) {
  __shared__ __align__(16) unsigned short ldsA[2][256 * 32];
  __shared__ __align__(16) unsigned short ldsB[2][128 * 32];
  const int K = 512;
  const int tid = threadIdx.x;
  const int wv = tid >> 6, ln = tid & 63;
  const int wr = wv >> 1, wc = wv & 1;
  int wg = xcd_swz(blockIdx.x, gridDim.x);
  int rowp = wg >> 2;
  int colp = wg & 3;
  const int row0 = rowp * 256;
  const int col0 = colp * 128;

  const int Ni = meta[0], L0 = meta[1], lim2 = meta[2];
  const bool internal = row0 < L0;      // L0 is 256-aligned -> no straddle
  const int limit = internal ? Ni : lim2;
  if (row0 >= limit) return;
  const unsigned short* __restrict__ Bt = internal ? Ub : Wb;

  f32x4 acc[4][4] = {};
  ushort4 sto[4][4];                    // packed bf16 inter-gate storage

  // global step s in [0,48): pass p = s>>4, gate g = (2*p)%3, k0 = (s&15)*32
  auto stage = [&](int buf, int s) {
    int p  = s >> 4;
    int g  = (2 * p) % 3;               // 0 -> i, 1 -> u(rows 1024+), 2 -> o(rows 512+)
    int k0 = (s & 15) * 32;
#pragma unroll
    for (int rep = 0; rep < 2; ++rep) {
      int cidx = rep * 512 + tid;
      int r  = cidx >> 2;
      int kc = cidx & 3;
      int kp = (kc ^ ((r >> 1) & 3)) * 8;
      int ga = row0 + r; if (ga > limit - 1) ga = limit - 1;
      const unsigned short* srcA = Zp + (size_t)ga * K + k0 + kp;
      __builtin_amdgcn_global_load_lds(
          (const __attribute__((address_space(1))) void*)(void*)srcA,
          (__attribute__((address_space(3))) void*)(&ldsA[buf][(size_t)cidx * 8]),
          16, 0, 0);
    }
    {
      int cidx = tid;
      int r  = cidx >> 2;
      int kc = cidx & 3;
      int kp = (kc ^ ((r >> 1) & 3)) * 8;
      const unsigned short* srcB = Bt + (size_t)(g * 512 + col0 + r) * K + k0 + kp;
      __builtin_amdgcn_global_load_lds(
          (const __attribute__((address_space(1))) void*)(void*)srcB,
          (__attribute__((address_space(3))) void*)(&ldsB[buf][(size_t)cidx * 8]),
          16, 0, 0);
    }
  };

  const int kcr = ((ln >> 4) ^ ((ln >> 1) & 3)) * 8;
  auto compute = [&](int buf) {
    bf16x8 af[4], bfr[4];
#pragma unroll
    for (int mi = 0; mi < 4; ++mi)
      af[mi] = *(const bf16x8*)(&ldsA[buf][(size_t)(wr * 64 + mi * 16 + (ln & 15)) * 32 + kcr]);
#pragma unroll
    for (int ni = 0; ni < 4; ++ni)
      bfr[ni] = *(const bf16x8*)(&ldsB[buf][(size_t)(wc * 64 + ni * 16 + (ln & 15)) * 32 + kcr]);
#pragma unroll
    for (int mi = 0; mi < 4; ++mi)
#pragma unroll
      for (int ni = 0; ni < 4; ++ni)
        acc[mi][ni] = __builtin_amdgcn_mfma_f32_16x16x32_bf16(bfr[ni], af[mi], acc[mi][ni], 0, 0, 0);
  };

  stage(0, 0);
  int cur = 0;

  // ---- pass 0 = i gate: steps 0..15 ----
#pragma unroll
  for (int s = 0; s < 16; ++s) {
    stage(cur ^ 1, s + 1);
    asm volatile("s_waitcnt vmcnt(3)" ::: "memory");
    __builtin_amdgcn_s_barrier();
    compute(cur);
    __builtin_amdgcn_s_barrier();
    cur ^= 1;
  }
#pragma unroll
  for (int ni = 0; ni < 4; ++ni) {
    int gn = col0 + wc * 64 + ni * 16 + (ln >> 4) * 4;
    float4 bv = *(const float4*)(bias + gn);            // b_i
#pragma unroll
    for (int mi = 0; mi < 4; ++mi) {
      float4 t;
      t.x = sigm(acc[mi][ni][0] + bv.x);
      t.y = sigm(acc[mi][ni][1] + bv.y);
      t.z = sigm(acc[mi][ni][2] + bv.z);
      t.w = sigm(acc[mi][ni][3] + bv.w);
      sto[mi][ni] = cvt4(t);                            // sigma(i)
      acc[mi][ni] = (f32x4){0.f, 0.f, 0.f, 0.f};
    }
  }

  // ---- pass 1 = u gate: steps 16..31 ----
#pragma unroll
  for (int s = 16; s < 32; ++s) {
    stage(cur ^ 1, s + 1);
    asm volatile("s_waitcnt vmcnt(3)" ::: "memory");
    __builtin_amdgcn_s_barrier();
    compute(cur);
    __builtin_amdgcn_s_barrier();
    cur ^= 1;
  }
#pragma unroll
  for (int ni = 0; ni < 4; ++ni) {
    int gn = col0 + wc * 64 + ni * 16 + (ln >> 4) * 4;
    float4 bv = *(const float4*)(bias + 1024 + gn);     // b_u
#pragma unroll
    for (int mi = 0; mi < 4; ++mi) {
      int m = row0 + wr * 64 + mi * 16 + (ln & 15);
      int mc = (m > limit - 1) ? (limit - 1) : m;       // clamp credb read in-bounds
      ushort4 cr = (ushort4){0, 0, 0, 0};
      if (internal) cr = *(const ushort4*)(credb + (size_t)mc * 512 + gn);
      float4 t;
      t.x = bf2f(sto[mi][ni].x) * tanh_f(acc[mi][ni][0] + bv.x) + bf2f(cr.x);
      t.y = bf2f(sto[mi][ni].y) * tanh_f(acc[mi][ni][1] + bv.y) + bf2f(cr.y);
      t.z = bf2f(sto[mi][ni].z) * tanh_f(acc[mi][ni][2] + bv.z) + bf2f(cr.z);
      t.w = bf2f(sto[mi][ni].w) * tanh_f(acc[mi][ni][3] + bv.w) + bf2f(cr.w);
      sto[mi][ni] = cvt4(t);                            // cc (bf16)
      acc[mi][ni] = (f32x4){0.f, 0.f, 0.f, 0.f};
    }
  }

  // ---- pass 2 = o gate: steps 32..47 ----
#pragma unroll
  for (int s = 32; s < 47; ++s) {
    stage(cur ^ 1, s + 1);
    asm volatile("s_waitcnt vmcnt(3)" ::: "memory");
    __builtin_amdgcn_s_barrier();
    compute(cur);
    __builtin_amdgcn_s_barrier();
    cur ^= 1;
  }
  asm volatile("s_waitcnt vmcnt(0)" ::: "memory");
  __builtin_amdgcn_s_barrier();
  compute(cur);

  const size_t cOff = (size_t)Nn * 512;
#pragma unroll
  for (int mi = 0; mi < 4; ++mi) {
    int m = row0 + wr * 64 + mi * 16 + (ln & 15);
    if (m >= limit) continue;
    int node = nodeof[m];
    size_t hb = (size_t)node * 512;
#pragma unroll
    for (int ni = 0; ni < 4; ++ni) {
      int gn = col0 + wc * 64 + ni * 16 + (ln >> 4) * 4;
      float4 bv = *(const float4*)(bias + 512 + gn);    // b_o
      float4 cn, hn;
      cn.x = bf2f(sto[mi][ni].x); cn.y = bf2f(sto[mi][ni].y);
      cn.z = bf2f(sto[mi][ni].z); cn.w = bf2f(sto[mi][ni].w);
      hn.x = sigm(acc[mi][ni][0] + bv.x) * tanh_f(cn.x);
      hn.y = sigm(acc[mi][ni][1] + bv.y) * tanh_f(cn.y);
      hn.z = sigm(acc[mi][ni][2] + bv.z) * tanh_f(cn.z);
      hn.w = sigm(acc[mi][ni][3] + bv.w) * tanh_f(cn.w);
      *(float4*)(out + hb + gn)        = hn;
      *(float4*)(out + cOff + hb + gn) = cn;
    }
  }
}

extern "C" void kernel_launch(void* const* d_in, const int* in_sizes, int n_in,
                              void* d_out, int out_size, void* d_ws, size_t ws_size,
                              hipStream_t stream) {
  const float* x     = (const float*)d_in[0];
  const float* h     = (const float*)d_in[1];
  const float* c     = (const float*)d_in[2];
  const int* child   = (const int*)d_in[3];
  const int* parent  = (const int*)d_in[4];
  const float* W_iou = (const float*)d_in[5];
  const float* U_iou = (const float*)d_in[6];
  const float* b_iou = (const float*)d_in[7];
  const float* U_f_w = (const float*)d_in[8];
  const float* U_f_b = (const float*)d_in[9];

  const int Nn = in_sizes[0] / 512;   // 100000
  const int M  = in_sizes[3];         // 99999

  float* out = (float*)d_out;

  // ---- workspace arena ----
  char* ws = (char*)d_ws;
  auto al = [](size_t v) { return (v + 255) & ~(size_t)255; };
  size_t szFc   = al((size_t)Nn * 512 * 2);           // fc (bf16)
  size_t offZp  = szFc;
  size_t szZp   = al((size_t)(Nn + 256) * 512 * 2);   // Zp by slot
  size_t offHb  = offZp + szZp;
  size_t szHb   = al((size_t)Nn * 512 * 2);
  size_t offCr  = offHb + szHb;
  size_t szCr   = al((size_t)(Nn + 512) * 512 * 2);   // credb by slot (+ clamp slack)
  size_t offDeg = offCr + szCr;
  size_t szN4   = al((size_t)Nn * 4);
  size_t offRs  = offDeg + szN4;
  size_t offCur = offRs + szN4;
  size_t offSl  = offCur + szN4;
  size_t offNo  = offSl + szN4;
  size_t szNo   = al((size_t)(Nn + 256) * 4);
  size_t offPs  = offNo + szNo;
  size_t szPs   = al((size_t)Nn * 8);
  size_t offCl  = offPs + szPs;
  size_t szCl   = al((size_t)M * 4);
  size_t offBs  = offCl + szCl;
  size_t szBs   = al(512 * 8);
  size_t offMt  = offBs + szBs;
  size_t szMt   = 256;
  size_t offWf  = offMt + szMt;
  size_t szWf   = al(512 * 512 * 2);
  size_t offUb  = offWf + szWf;
  size_t szUw   = al((size_t)1536 * 512 * 2);
  size_t offWb  = offUb + szUw;
  size_t needed = offWb + szUw;
  if (ws_size < needed) return;

  unsigned short* fcb   = (unsigned short*)(ws);
  unsigned short* Zp    = (unsigned short*)(ws + offZp);
  unsigned short* hbuf  = (unsigned short*)(ws + offHb);
  unsigned short* credb = (unsigned short*)(ws + offCr);
  int*            deg   = (int*)(ws + offDeg);
  int*            rs    = (int*)(ws + offRs);
  int*            cursor= (int*)(ws + offCur);
  int*            slot  = (int*)(ws + offSl);
  int*            nodeof= (int*)(ws + offNo);
  unsigned long long* ps   = (unsigned long long*)(ws + offPs);
  int*            clist = (int*)(ws + offCl);
  unsigned long long* bsum = (unsigned long long*)(ws + offBs);
  int*            meta  = (int*)(ws + offMt);
  unsigned short* Wf    = (unsigned short*)(ws + offWf);
  unsigned short* Ub    = (unsigned short*)(ws + offUb);
  unsigned short* Wb    = (unsigned short*)(ws + offWb);

  hipMemsetAsync(deg, 0, (size_t)Nn * 4, stream);

  // 1. conversions
  long long n8h = (long long)Nn * 512 / 8;
  k_f2bf<<<(int)((n8h + 255) / 256), 256, 0, stream>>>(h, hbuf, n8h);
  k_f2bf<<<(512 * 512 / 8 + 255) / 256, 256, 0, stream>>>(U_f_w, Wf, 512 * 512 / 8);
  k_f2bf<<<(1536 * 512 / 8 + 255) / 256, 256, 0, stream>>>(U_iou, Ub, 1536 * 512 / 8);
  k_f2bf<<<(1536 * 512 / 8 + 255) / 256, 256, 0, stream>>>(W_iou, Wb, 1536 * 512 / 8);

  // 2. CSR + partition build
  int nb1 = (Nn + 255) / 256;
  k_hist<<<(M + 255) / 256, 256, 0, stream>>>(parent, deg, M);
  k_scan1<<<nb1, 256, 0, stream>>>(deg, ps, bsum, Nn);
  k_scan2<<<1, 512, 0, stream>>>(bsum, nb1, meta, Nn);
  k_scan3<<<nb1, 256, 0, stream>>>(ps, bsum, meta, deg, rs, cursor, slot, nodeof, Nn);
  k_fill<<<(M + 255) / 256, 256, 0, stream>>>(parent, child, cursor, clist, M);

  // 3. fc = sigmoid(hbuf @ Wf^T + U_f_b) * c   [N,512] bf16
  int nbyF = (Nn + 255) / 256;
  k_gemm_f<<<nbyF * 4, 512, 0, stream>>>(hbuf, Wf, U_f_b, c, fcb, Nn);

  // 4. gather-reduce -> Zp, credb (both slot-order)
  k_reduce<<<(Nn + 3) / 4, 256, 0, stream>>>(hbuf, fcb, x, rs, clist, slot, Zp, credb, Nn, M);

  // 5+6. fused iou GEMM (gate passes i -> u -> o) + LSTM epilogue -> out directly
  int nbyI = (Nn >> 8) + 2;
  k_gemm_iou_fused<<<nbyI * 4, 512, 0, stream>>>(Zp, Ub, Wb, b_iou, meta, nodeof, credb, out, Nn);
}

// Round 12
// 733.384 us; speedup vs baseline: 1.1741x; 1.1741x over previous
//
#include <hip/hip_runtime.h>
#include <stdint.h>

typedef __bf16 bf16x8 __attribute__((ext_vector_type(8)));
typedef float f32x4 __attribute__((ext_vector_type(4)));
typedef unsigned short ushort8 __attribute__((ext_vector_type(8)));

__device__ __forceinline__ float bf2f(unsigned short u) {
  union { uint32_t i; float f; } v; v.i = ((uint32_t)u) << 16; return v.f;
}
__device__ __forceinline__ unsigned short f2bf(float f) {
  union { uint32_t i; float f; } v; v.f = f;
  uint32_t u = v.i;
  return (unsigned short)((u + 0x7fffu + ((u >> 16) & 1u)) >> 16);
}
__device__ __forceinline__ float sigm(float x) { return 1.0f / (1.0f + __expf(-x)); }
__device__ __forceinline__ float tanh_f(float x) { return 1.0f - 2.0f / (__expf(2.0f * x) + 1.0f); }

__device__ __forceinline__ ushort4 cvt4(float4 a) {
  ushort4 o; o.x = f2bf(a.x); o.y = f2bf(a.y); o.z = f2bf(a.z); o.w = f2bf(a.w); return o;
}

// bijective XCD-aware remap (m204)
__device__ __forceinline__ int xcd_swz(int bid, int nwg) {
  int q = nwg >> 3, r = nwg & 7;
  int x = bid & 7, idx = bid >> 3;
  return (x < r ? x * (q + 1) : r * (q + 1) + (x - r) * q) + idx;
}

// ---------- fp32 -> bf16 bulk convert ----------
__global__ void k_f2bf(const float* __restrict__ src, unsigned short* __restrict__ dst, long long n8) {
  long long t = (long long)blockIdx.x * blockDim.x + threadIdx.x;
  if (t >= n8) return;
  const float4* s = (const float4*)src + t * 2;
  float4 a = s[0], b = s[1];
  ((ushort4*)dst)[t * 2]     = cvt4(a);
  ((ushort4*)dst)[t * 2 + 1] = cvt4(b);
}

// ---------- degree histogram ----------
__global__ void k_hist(const int* __restrict__ parent, int* __restrict__ deg, int M) {
  int e = blockIdx.x * blockDim.x + threadIdx.x;
  if (e < M) atomicAdd(&deg[parent[e]], 1);
}

// ---------- packed scan pass 1 ----------
__global__ void k_scan1(const int* __restrict__ deg, unsigned long long* __restrict__ ps,
                        unsigned long long* __restrict__ bsum, int Nn) {
  __shared__ unsigned long long tmp[256];
  int t = blockIdx.x * 256 + threadIdx.x;
  int d = (t < Nn) ? deg[t] : 0;
  unsigned long long v = (unsigned long long)(unsigned)d | ((d > 0) ? (1ull << 32) : 0ull);
  tmp[threadIdx.x] = v;
  __syncthreads();
#pragma unroll
  for (int s = 1; s < 256; s <<= 1) {
    unsigned long long a = (threadIdx.x >= (unsigned)s) ? tmp[threadIdx.x - s] : 0;
    __syncthreads();
    tmp[threadIdx.x] += a;
    __syncthreads();
  }
  if (t < Nn) ps[t] = tmp[threadIdx.x] - v;
  if (threadIdx.x == 255) bsum[blockIdx.x] = tmp[255];
}

// ---------- scan pass 2 + meta (L0 256-aligned for 256-row panels) ----------
__global__ void k_scan2(unsigned long long* __restrict__ bsum, int nb,
                        int* __restrict__ meta, int Nn) {
  __shared__ unsigned long long tmp[512];
  int i = threadIdx.x;
  unsigned long long v = (i < nb) ? bsum[i] : 0;
  tmp[i] = v;
  __syncthreads();
#pragma unroll
  for (int s = 1; s < 512; s <<= 1) {
    unsigned long long a = (i >= s) ? tmp[i - s] : 0;
    __syncthreads();
    tmp[i] += a;
    __syncthreads();
  }
  if (i < nb) bsum[i] = tmp[i] - v;
  if (i == 511) {
    int Ni = (int)(tmp[511] >> 32);
    int L0 = ((Ni + 255) >> 8) << 8;   // 256-aligned leaf base
    meta[0] = Ni;
    meta[1] = L0;
    meta[2] = L0 + (Nn - Ni);
  }
}

// ---------- scan pass 3: rs/cursor + slot + nodeof ----------
__global__ void k_scan3(const unsigned long long* __restrict__ ps,
                        const unsigned long long* __restrict__ bsum,
                        const int* __restrict__ meta, const int* __restrict__ deg,
                        int* __restrict__ rs, int* __restrict__ cursor,
                        int* __restrict__ slot, int* __restrict__ nodeof, int Nn) {
  int t = blockIdx.x * 256 + threadIdx.x;
  if (t >= Nn) return;
  unsigned long long p = ps[t] + bsum[blockIdx.x];
  int r  = (int)(p & 0xffffffffull);
  int si = (int)(p >> 32);
  rs[t] = r;
  cursor[t] = r;
  int sl = (deg[t] > 0) ? si : (meta[1] + (t - si));
  slot[t] = sl;
  nodeof[sl] = t;
}

// ---------- bucket edges by parent ----------
__global__ void k_fill(const int* __restrict__ parent, const int* __restrict__ child,
                       int* __restrict__ cursor, int* __restrict__ childlist, int M) {
  int e = blockIdx.x * blockDim.x + threadIdx.x;
  if (e >= M) return;
  int p = parent[e];
  int pos = atomicAdd(&cursor[p], 1);
  childlist[pos] = child[e];
}

// ---------- gather-reduce: Zp[slot]=bf16(sum h_ch | x); credb[node]=bf16(sum fc_ch) ----------
__global__ void k_reduce(const unsigned short* __restrict__ hbuf,
                         const unsigned short* __restrict__ fcb, const float* __restrict__ x,
                         const int* __restrict__ rs, const int* __restrict__ childlist,
                         const int* __restrict__ slot,
                         unsigned short* __restrict__ Zp, unsigned short* __restrict__ credb,
                         int Nn, int M) {
  int p = blockIdx.x * 4 + (threadIdx.x >> 6);
  if (p >= Nn) return;
  int ln = threadIdx.x & 63;
  int j = ln * 8;
  int start = rs[p];
  int end = (p + 1 < Nn) ? rs[p + 1] : M;
  size_t zb = (size_t)slot[p] * 512 + j;
  if (end > start) {
    float hs[8] = {0, 0, 0, 0, 0, 0, 0, 0};
    float cs[8] = {0, 0, 0, 0, 0, 0, 0, 0};
    for (int i = start; i < end; ++i) {
      int ch = childlist[i];
      size_t cb = (size_t)ch * 512 + j;
      ushort8 hv = *(const ushort8*)(hbuf + cb);
      ushort8 fv = *(const ushort8*)(fcb + cb);
#pragma unroll
      for (int q = 0; q < 8; ++q) {
        hs[q] += bf2f(hv[q]);
        cs[q] += bf2f(fv[q]);
      }
    }
    float4 h0 = {hs[0], hs[1], hs[2], hs[3]}, h1 = {hs[4], hs[5], hs[6], hs[7]};
    float4 c0 = {cs[0], cs[1], cs[2], cs[3]}, c1 = {cs[4], cs[5], cs[6], cs[7]};
    ((ushort4*)(Zp + zb))[0] = cvt4(h0);
    ((ushort4*)(Zp + zb))[1] = cvt4(h1);
    size_t cr = (size_t)p * 512 + j;
    ((ushort4*)(credb + cr))[0] = cvt4(c0);
    ((ushort4*)(credb + cr))[1] = cvt4(c1);
  } else {
    const float4* s = (const float4*)(x + (size_t)p * 512 + j);
    float4 x0 = s[0], x1 = s[1];
    ((ushort4*)(Zp + zb))[0] = cvt4(x0);
    ((ushort4*)(Zp + zb))[1] = cvt4(x1);
  }
}

// ---------- f-gate GEMM: 256x128, 8 waves, single-barrier phased pipeline + T2 + T5 ----------
// fc = sigmoid(hbuf @ Wf^T + b) * c
__global__ __launch_bounds__(512)
void k_gemm_f(const unsigned short* __restrict__ A,
              const unsigned short* __restrict__ Bt,
              const float* __restrict__ bias, const float* __restrict__ cmat,
              unsigned short* __restrict__ C, int Mrows) {
  __shared__ __align__(16) unsigned short ldsA[2][256 * 32];
  __shared__ __align__(16) unsigned short ldsB[2][128 * 32];
  const int K = 512, ldc = 512;
  const int tid = threadIdx.x;
  const int wv = tid >> 6, ln = tid & 63;
  const int wr = wv >> 1, wc = wv & 1;
  int wg = xcd_swz(blockIdx.x, gridDim.x);
  int rowp = wg >> 2;
  int colp = wg & 3;
  const int row0 = rowp * 256;
  const int col0 = colp * 128;

  f32x4 acc[4][4] = {};

  auto stageA = [&](int buf, int k0, int rep) {
    int cidx = rep * 512 + tid;
    int r  = cidx >> 2;
    int kc = cidx & 3;
    int kp = (kc ^ ((r >> 1) & 3)) * 8;
    int ga = row0 + r; if (ga > Mrows - 1) ga = Mrows - 1;
    const unsigned short* srcA = A + (size_t)ga * K + k0 + kp;
    __builtin_amdgcn_global_load_lds(
        (const __attribute__((address_space(1))) void*)(void*)srcA,
        (__attribute__((address_space(3))) void*)(&ldsA[buf][(size_t)cidx * 8]),
        16, 0, 0);
  };
  auto stageB = [&](int buf, int k0) {
    int cidx = tid;
    int r  = cidx >> 2;
    int kc = cidx & 3;
    int kp = (kc ^ ((r >> 1) & 3)) * 8;
    const unsigned short* srcB = Bt + (size_t)(col0 + r) * K + k0 + kp;
    __builtin_amdgcn_global_load_lds(
        (const __attribute__((address_space(1))) void*)(void*)srcB,
        (__attribute__((address_space(3))) void*)(&ldsB[buf][(size_t)cidx * 8]),
        16, 0, 0);
  };

  const int kcr = ((ln >> 4) ^ ((ln >> 1) & 3)) * 8;

  stageA(0, 0, 0); stageA(0, 0, 1); stageB(0, 0);
  int cur = 0;
#pragma unroll
  for (int kt = 0; kt < 16; ++kt) {
    // own tile-kt loads drained, then join: all waves' loads landed; buf^1 free to stage
    asm volatile("s_waitcnt vmcnt(0)" ::: "memory");
    __builtin_amdgcn_s_barrier();
    const bool pre = (kt < 15);
    const int nk0 = (kt + 1) * 32;

    bf16x8 bfr[4];
#pragma unroll
    for (int ni = 0; ni < 4; ++ni)
      bfr[ni] = *(const bf16x8*)(&ldsB[cur][(size_t)(wc * 64 + ni * 16 + (ln & 15)) * 32 + kcr]);

    // phase 0
    if (pre) stageA(cur ^ 1, nk0, 0);
    {
      bf16x8 af = *(const bf16x8*)(&ldsA[cur][(size_t)(wr * 64 + 0 * 16 + (ln & 15)) * 32 + kcr]);
      __builtin_amdgcn_s_setprio(1);
#pragma unroll
      for (int ni = 0; ni < 4; ++ni)
        acc[0][ni] = __builtin_amdgcn_mfma_f32_16x16x32_bf16(bfr[ni], af, acc[0][ni], 0, 0, 0);
      __builtin_amdgcn_s_setprio(0);
    }
    // phase 1
    if (pre) stageA(cur ^ 1, nk0, 1);
    {
      bf16x8 af = *(const bf16x8*)(&ldsA[cur][(size_t)(wr * 64 + 1 * 16 + (ln & 15)) * 32 + kcr]);
      __builtin_amdgcn_s_setprio(1);
#pragma unroll
      for (int ni = 0; ni < 4; ++ni)
        acc[1][ni] = __builtin_amdgcn_mfma_f32_16x16x32_bf16(bfr[ni], af, acc[1][ni], 0, 0, 0);
      __builtin_amdgcn_s_setprio(0);
    }
    // phase 2
    if (pre) stageB(cur ^ 1, nk0);
    {
      bf16x8 af = *(const bf16x8*)(&ldsA[cur][(size_t)(wr * 64 + 2 * 16 + (ln & 15)) * 32 + kcr]);
      __builtin_amdgcn_s_setprio(1);
#pragma unroll
      for (int ni = 0; ni < 4; ++ni)
        acc[2][ni] = __builtin_amdgcn_mfma_f32_16x16x32_bf16(bfr[ni], af, acc[2][ni], 0, 0, 0);
      __builtin_amdgcn_s_setprio(0);
    }
    // phase 3
    {
      bf16x8 af = *(const bf16x8*)(&ldsA[cur][(size_t)(wr * 64 + 3 * 16 + (ln & 15)) * 32 + kcr]);
      __builtin_amdgcn_s_setprio(1);
#pragma unroll
      for (int ni = 0; ni < 4; ++ni)
        acc[3][ni] = __builtin_amdgcn_mfma_f32_16x16x32_bf16(bfr[ni], af, acc[3][ni], 0, 0, 0);
      __builtin_amdgcn_s_setprio(0);
    }
    cur ^= 1;
  }

#pragma unroll
  for (int mi = 0; mi < 4; ++mi) {
    int gm = row0 + wr * 64 + mi * 16 + (ln & 15);
    if (gm >= Mrows) continue;
#pragma unroll
    for (int ni = 0; ni < 4; ++ni) {
      int gn = col0 + wc * 64 + ni * 16 + (ln >> 4) * 4;
      float4 bv = *(const float4*)(bias + gn);
      float4 cv = *(const float4*)(cmat + (size_t)gm * ldc + gn);
      ushort4 o;
      o.x = f2bf(sigm(acc[mi][ni][0] + bv.x) * cv.x);
      o.y = f2bf(sigm(acc[mi][ni][1] + bv.y) * cv.y);
      o.z = f2bf(sigm(acc[mi][ni][2] + bv.z) * cv.z);
      o.w = f2bf(sigm(acc[mi][ni][3] + bv.w) * cv.w);
      *(ushort4*)(C + (size_t)gm * ldc + gn) = o;
    }
  }
}

// ---------- iou GEMM: 256x128, 8 waves, single-barrier phased pipeline + T2 + T5 ----------
// iou[node] = Zp @ (U|W)^T + b
__global__ __launch_bounds__(512)
void k_gemm_iou(const unsigned short* __restrict__ Zp,
                const unsigned short* __restrict__ Ub,
                const unsigned short* __restrict__ Wb,
                const float* __restrict__ bias,
                const int* __restrict__ meta,
                const int* __restrict__ nodeof,
                unsigned short* __restrict__ C) {
  __shared__ __align__(16) unsigned short ldsA[2][256 * 32];
  __shared__ __align__(16) unsigned short ldsB[2][128 * 32];
  const int K = 512, ldc = 1536;
  const int tid = threadIdx.x;
  const int wv = tid >> 6, ln = tid & 63;
  const int wr = wv >> 1, wc = wv & 1;
  int wg = xcd_swz(blockIdx.x, gridDim.x);
  int rowp = wg / 12;
  int colp = wg - rowp * 12;
  const int row0 = rowp * 256;
  const int col0 = colp * 128;

  const int Ni = meta[0], L0 = meta[1], lim2 = meta[2];
  const bool internal = row0 < L0;
  const int limit = internal ? Ni : lim2;
  if (row0 >= limit) return;
  const unsigned short* __restrict__ Bt = internal ? Ub : Wb;

  f32x4 acc[4][4] = {};

  auto stageA = [&](int buf, int k0, int rep) {
    int cidx = rep * 512 + tid;
    int r  = cidx >> 2;
    int kc = cidx & 3;
    int kp = (kc ^ ((r >> 1) & 3)) * 8;
    int ga = row0 + r; if (ga > limit - 1) ga = limit - 1;
    const unsigned short* srcA = Zp + (size_t)ga * K + k0 + kp;
    __builtin_amdgcn_global_load_lds(
        (const __attribute__((address_space(1))) void*)(void*)srcA,
        (__attribute__((address_space(3))) void*)(&ldsA[buf][(size_t)cidx * 8]),
        16, 0, 0);
  };
  auto stageB = [&](int buf, int k0) {
    int cidx = tid;
    int r  = cidx >> 2;
    int kc = cidx & 3;
    int kp = (kc ^ ((r >> 1) & 3)) * 8;
    const unsigned short* srcB = Bt + (size_t)(col0 + r) * K + k0 + kp;
    __builtin_amdgcn_global_load_lds(
        (const __attribute__((address_space(1))) void*)(void*)srcB,
        (__attribute__((address_space(3))) void*)(&ldsB[buf][(size_t)cidx * 8]),
        16, 0, 0);
  };

  const int kcr = ((ln >> 4) ^ ((ln >> 1) & 3)) * 8;

  stageA(0, 0, 0); stageA(0, 0, 1); stageB(0, 0);
  int cur = 0;
#pragma unroll
  for (int kt = 0; kt < 16; ++kt) {
    asm volatile("s_waitcnt vmcnt(0)" ::: "memory");
    __builtin_amdgcn_s_barrier();
    const bool pre = (kt < 15);
    const int nk0 = (kt + 1) * 32;

    bf16x8 bfr[4];
#pragma unroll
    for (int ni = 0; ni < 4; ++ni)
      bfr[ni] = *(const bf16x8*)(&ldsB[cur][(size_t)(wc * 64 + ni * 16 + (ln & 15)) * 32 + kcr]);

    if (pre) stageA(cur ^ 1, nk0, 0);
    {
      bf16x8 af = *(const bf16x8*)(&ldsA[cur][(size_t)(wr * 64 + 0 * 16 + (ln & 15)) * 32 + kcr]);
      __builtin_amdgcn_s_setprio(1);
#pragma unroll
      for (int ni = 0; ni < 4; ++ni)
        acc[0][ni] = __builtin_amdgcn_mfma_f32_16x16x32_bf16(bfr[ni], af, acc[0][ni], 0, 0, 0);
      __builtin_amdgcn_s_setprio(0);
    }
    if (pre) stageA(cur ^ 1, nk0, 1);
    {
      bf16x8 af = *(const bf16x8*)(&ldsA[cur][(size_t)(wr * 64 + 1 * 16 + (ln & 15)) * 32 + kcr]);
      __builtin_amdgcn_s_setprio(1);
#pragma unroll
      for (int ni = 0; ni < 4; ++ni)
        acc[1][ni] = __builtin_amdgcn_mfma_f32_16x16x32_bf16(bfr[ni], af, acc[1][ni], 0, 0, 0);
      __builtin_amdgcn_s_setprio(0);
    }
    if (pre) stageB(cur ^ 1, nk0);
    {
      bf16x8 af = *(const bf16x8*)(&ldsA[cur][(size_t)(wr * 64 + 2 * 16 + (ln & 15)) * 32 + kcr]);
      __builtin_amdgcn_s_setprio(1);
#pragma unroll
      for (int ni = 0; ni < 4; ++ni)
        acc[2][ni] = __builtin_amdgcn_mfma_f32_16x16x32_bf16(bfr[ni], af, acc[2][ni], 0, 0, 0);
      __builtin_amdgcn_s_setprio(0);
    }
    {
      bf16x8 af = *(const bf16x8*)(&ldsA[cur][(size_t)(wr * 64 + 3 * 16 + (ln & 15)) * 32 + kcr]);
      __builtin_amdgcn_s_setprio(1);
#pragma unroll
      for (int ni = 0; ni < 4; ++ni)
        acc[3][ni] = __builtin_amdgcn_mfma_f32_16x16x32_bf16(bfr[ni], af, acc[3][ni], 0, 0, 0);
      __builtin_amdgcn_s_setprio(0);
    }
    cur ^= 1;
  }

#pragma unroll
  for (int mi = 0; mi < 4; ++mi) {
    int m = row0 + wr * 64 + mi * 16 + (ln & 15);
    if (m >= limit) continue;
    int node = nodeof[m];
    size_t ob = (size_t)node * ldc;
#pragma unroll
    for (int ni = 0; ni < 4; ++ni) {
      int gn = col0 + wc * 64 + ni * 16 + (ln >> 4) * 4;
      float4 bv = *(const float4*)(bias + gn);
      ushort4 o;
      o.x = f2bf(acc[mi][ni][0] + bv.x);
      o.y = f2bf(acc[mi][ni][1] + bv.y);
      o.z = f2bf(acc[mi][ni][2] + bv.z);
      o.w = f2bf(acc[mi][ni][3] + bv.w);
      *(ushort4*)(C + ob + gn) = o;
    }
  }
}

// ---------- LSTM epilogue: fully coalesced (node-order iou + credb) ----------
__global__ void k_epilogue(const unsigned short* __restrict__ iou,
                           const unsigned short* __restrict__ credb,
                           const int* __restrict__ deg,
                           float* __restrict__ out, int Nn) {
  long long t = (long long)blockIdx.x * blockDim.x + threadIdx.x;
  int n = (int)(t >> 6);
  if (n >= Nn) return;
  int j = ((int)t & 63) * 8;
  size_t ib = (size_t)n * 1536;
  ushort4 iv0 = *(const ushort4*)(iou + ib + j);
  ushort4 iv1 = *(const ushort4*)(iou + ib + j + 4);
  ushort4 ov0 = *(const ushort4*)(iou + ib + 512 + j);
  ushort4 ov1 = *(const ushort4*)(iou + ib + 512 + j + 4);
  ushort4 uv0 = *(const ushort4*)(iou + ib + 1024 + j);
  ushort4 uv1 = *(const ushort4*)(iou + ib + 1024 + j + 4);

  float carr[8] = {0, 0, 0, 0, 0, 0, 0, 0};
  if (deg[n] > 0) {
    size_t cr = (size_t)n * 512 + j;
    ushort4 c0 = *(const ushort4*)(credb + cr);
    ushort4 c1 = *(const ushort4*)(credb + cr + 4);
    carr[0] = bf2f(c0.x); carr[1] = bf2f(c0.y); carr[2] = bf2f(c0.z); carr[3] = bf2f(c0.w);
    carr[4] = bf2f(c1.x); carr[5] = bf2f(c1.y); carr[6] = bf2f(c1.z); carr[7] = bf2f(c1.w);
  }

  float iarr[8] = {bf2f(iv0.x), bf2f(iv0.y), bf2f(iv0.z), bf2f(iv0.w),
                   bf2f(iv1.x), bf2f(iv1.y), bf2f(iv1.z), bf2f(iv1.w)};
  float oarr[8] = {bf2f(ov0.x), bf2f(ov0.y), bf2f(ov0.z), bf2f(ov0.w),
                   bf2f(ov1.x), bf2f(ov1.y), bf2f(ov1.z), bf2f(ov1.w)};
  float uarr[8] = {bf2f(uv0.x), bf2f(uv0.y), bf2f(uv0.z), bf2f(uv0.w),
                   bf2f(uv1.x), bf2f(uv1.y), bf2f(uv1.z), bf2f(uv1.w)};
  float hn[8], cn[8];
#pragma unroll
  for (int q = 0; q < 8; ++q) {
    float cc = sigm(iarr[q]) * tanh_f(uarr[q]) + carr[q];
    cn[q] = cc;
    hn[q] = sigm(oarr[q]) * tanh_f(cc);
  }
  size_t hb = (size_t)n * 512 + j;
  size_t cb = (size_t)Nn * 512 + hb;
  *(float4*)(out + hb)     = make_float4(hn[0], hn[1], hn[2], hn[3]);
  *(float4*)(out + hb + 4) = make_float4(hn[4], hn[5], hn[6], hn[7]);
  *(float4*)(out + cb)     = make_float4(cn[0], cn[1], cn[2], cn[3]);
  *(float4*)(out + cb + 4) = make_float4(cn[4], cn[5], cn[6], cn[7]);
}

extern "C" void kernel_launch(void* const* d_in, const int* in_sizes, int n_in,
                              void* d_out, int out_size, void* d_ws, size_t ws_size,
                              hipStream_t stream) {
  const float* x     = (const float*)d_in[0];
  const float* h     = (const float*)d_in[1];
  const float* c     = (const float*)d_in[2];
  const int* child   = (const int*)d_in[3];
  const int* parent  = (const int*)d_in[4];
  const float* W_iou = (const float*)d_in[5];
  const float* U_iou = (const float*)d_in[6];
  const float* b_iou = (const float*)d_in[7];
  const float* U_f_w = (const float*)d_in[8];
  const float* U_f_b = (const float*)d_in[9];

  const int Nn = in_sizes[0] / 512;   // 100000
  const int M  = in_sizes[3];         // 99999

  float* out = (float*)d_out;

  // ---- workspace arena (region0: fc then iou; disjoint lifetimes) ----
  char* ws = (char*)d_ws;
  auto al = [](size_t v) { return (v + 255) & ~(size_t)255; };
  size_t sz0    = al((size_t)Nn * 1536 * 2);          // fc (first 1/3) then iou (node-order)
  size_t offZp  = sz0;
  size_t szZp   = al((size_t)(Nn + 256) * 512 * 2);   // Zp by slot
  size_t offHb  = offZp + szZp;
  size_t szHb   = al((size_t)Nn * 512 * 2);
  size_t offCr  = offHb + szHb;
  size_t szCr   = al((size_t)Nn * 512 * 2);           // credb node-order
  size_t offDeg = offCr + szCr;
  size_t szN4   = al((size_t)Nn * 4);
  size_t offRs  = offDeg + szN4;
  size_t offCur = offRs + szN4;
  size_t offSl  = offCur + szN4;
  size_t offNo  = offSl + szN4;
  size_t szNo   = al((size_t)(Nn + 256) * 4);
  size_t offPs  = offNo + szNo;
  size_t szPs   = al((size_t)Nn * 8);
  size_t offCl  = offPs + szPs;
  size_t szCl   = al((size_t)M * 4);
  size_t offBs  = offCl + szCl;
  size_t szBs   = al(512 * 8);
  size_t offMt  = offBs + szBs;
  size_t szMt   = 256;
  size_t offWf  = offMt + szMt;
  size_t szWf   = al(512 * 512 * 2);
  size_t offUb  = offWf + szWf;
  size_t szUw   = al((size_t)1536 * 512 * 2);
  size_t offWb  = offUb + szUw;
  size_t needed = offWb + szUw;
  if (ws_size < needed) return;

  unsigned short* fcb   = (unsigned short*)(ws);
  unsigned short* iou   = (unsigned short*)(ws);
  unsigned short* Zp    = (unsigned short*)(ws + offZp);
  unsigned short* hbuf  = (unsigned short*)(ws + offHb);
  unsigned short* credb = (unsigned short*)(ws + offCr);
  int*            deg   = (int*)(ws + offDeg);
  int*            rs    = (int*)(ws + offRs);
  int*            cursor= (int*)(ws + offCur);
  int*            slot  = (int*)(ws + offSl);
  int*            nodeof= (int*)(ws + offNo);
  unsigned long long* ps   = (unsigned long long*)(ws + offPs);
  int*            clist = (int*)(ws + offCl);
  unsigned long long* bsum = (unsigned long long*)(ws + offBs);
  int*            meta  = (int*)(ws + offMt);
  unsigned short* Wf    = (unsigned short*)(ws + offWf);
  unsigned short* Ub    = (unsigned short*)(ws + offUb);
  unsigned short* Wb    = (unsigned short*)(ws + offWb);

  hipMemsetAsync(deg, 0, (size_t)Nn * 4, stream);

  // 1. conversions
  long long n8h = (long long)Nn * 512 / 8;
  k_f2bf<<<(int)((n8h + 255) / 256), 256, 0, stream>>>(h, hbuf, n8h);
  k_f2bf<<<(512 * 512 / 8 + 255) / 256, 256, 0, stream>>>(U_f_w, Wf, 512 * 512 / 8);
  k_f2bf<<<(1536 * 512 / 8 + 255) / 256, 256, 0, stream>>>(U_iou, Ub, 1536 * 512 / 8);
  k_f2bf<<<(1536 * 512 / 8 + 255) / 256, 256, 0, stream>>>(W_iou, Wb, 1536 * 512 / 8);

  // 2. CSR + partition build
  int nb1 = (Nn + 255) / 256;
  k_hist<<<(M + 255) / 256, 256, 0, stream>>>(parent, deg, M);
  k_scan1<<<nb1, 256, 0, stream>>>(deg, ps, bsum, Nn);
  k_scan2<<<1, 512, 0, stream>>>(bsum, nb1, meta, Nn);
  k_scan3<<<nb1, 256, 0, stream>>>(ps, bsum, meta, deg, rs, cursor, slot, nodeof, Nn);
  k_fill<<<(M + 255) / 256, 256, 0, stream>>>(parent, child, cursor, clist, M);

  // 3. fc = sigmoid(hbuf @ Wf^T + U_f_b) * c   [N,512] bf16
  int nbyF = (Nn + 255) / 256;
  k_gemm_f<<<nbyF * 4, 512, 0, stream>>>(hbuf, Wf, U_f_b, c, fcb, Nn);

  // 4. gather-reduce -> Zp (slot-order), credb (node-order)
  k_reduce<<<(Nn + 3) / 4, 256, 0, stream>>>(hbuf, fcb, x, rs, clist, slot, Zp, credb, Nn, M);

  // 5. iou[node] = Zp @ (U_iou|W_iou)^T + b_iou  (K=512, single-barrier phased pipeline)
  int nbyI = (Nn >> 8) + 2;
  k_gemm_iou<<<nbyI * 12, 512, 0, stream>>>(Zp, Ub, Wb, b_iou, meta, nodeof, iou);

  // 6. epilogue -> h_new, c_new (fully coalesced)
  k_epilogue<<<(int)(((long long)Nn * 64 + 255) / 256), 256, 0, stream>>>(iou, credb, deg, out, Nn);
}

// Round 13
// 698.022 us; speedup vs baseline: 1.2336x; 1.0507x over previous
//
#include <hip/hip_runtime.h>
#include <stdint.h>

typedef __bf16 bf16x8 __attribute__((ext_vector_type(8)));
typedef float f32x4 __attribute__((ext_vector_type(4)));
typedef unsigned short ushort8 __attribute__((ext_vector_type(8)));

__device__ __forceinline__ float bf2f(unsigned short u) {
  union { uint32_t i; float f; } v; v.i = ((uint32_t)u) << 16; return v.f;
}
__device__ __forceinline__ unsigned short f2bf(float f) {
  union { uint32_t i; float f; } v; v.f = f;
  uint32_t u = v.i;
  return (unsigned short)((u + 0x7fffu + ((u >> 16) & 1u)) >> 16);
}
__device__ __forceinline__ float sigm(float x) { return 1.0f / (1.0f + __expf(-x)); }
__device__ __forceinline__ float tanh_f(float x) { return 1.0f - 2.0f / (__expf(2.0f * x) + 1.0f); }

__device__ __forceinline__ ushort4 cvt4(float4 a) {
  ushort4 o; o.x = f2bf(a.x); o.y = f2bf(a.y); o.z = f2bf(a.z); o.w = f2bf(a.w); return o;
}

// bijective XCD-aware remap (m204)
__device__ __forceinline__ int xcd_swz(int bid, int nwg) {
  int q = nwg >> 3, r = nwg & 7;
  int x = bid & 7, idx = bid >> 3;
  return (x < r ? x * (q + 1) : r * (q + 1) + (x - r) * q) + idx;
}

// ---------- fp32 -> bf16 bulk convert (weights) ----------
__global__ void k_f2bf(const float* __restrict__ src, unsigned short* __restrict__ dst, long long n8) {
  long long t = (long long)blockIdx.x * blockDim.x + threadIdx.x;
  if (t >= n8) return;
  const float4* s = (const float4*)src + t * 2;
  float4 a = s[0], b = s[1];
  ((ushort4*)dst)[t * 2]     = cvt4(a);
  ((ushort4*)dst)[t * 2 + 1] = cvt4(b);
}

// ---------- histogram (used for parent->deg and child->chdeg) ----------
__global__ void k_hist(const int* __restrict__ idx, int* __restrict__ cnt, int M) {
  int e = blockIdx.x * blockDim.x + threadIdx.x;
  if (e < M) atomicAdd(&cnt[idx[e]], 1);
}

// ---------- packed scan pass 1 (deg + has_child bit) ----------
__global__ void k_scan1(const int* __restrict__ deg, unsigned long long* __restrict__ ps,
                        unsigned long long* __restrict__ bsum, int Nn) {
  __shared__ unsigned long long tmp[256];
  int t = blockIdx.x * 256 + threadIdx.x;
  int d = (t < Nn) ? deg[t] : 0;
  unsigned long long v = (unsigned long long)(unsigned)d | ((d > 0) ? (1ull << 32) : 0ull);
  tmp[threadIdx.x] = v;
  __syncthreads();
#pragma unroll
  for (int s = 1; s < 256; s <<= 1) {
    unsigned long long a = (threadIdx.x >= (unsigned)s) ? tmp[threadIdx.x - s] : 0;
    __syncthreads();
    tmp[threadIdx.x] += a;
    __syncthreads();
  }
  if (t < Nn) ps[t] = tmp[threadIdx.x] - v;
  if (threadIdx.x == 255) bsum[blockIdx.x] = tmp[255];
}

// ---------- scan pass 2 + meta (L0 256-aligned for 256-row panels) ----------
__global__ void k_scan2(unsigned long long* __restrict__ bsum, int nb,
                        int* __restrict__ meta, int Nn) {
  __shared__ unsigned long long tmp[512];
  int i = threadIdx.x;
  unsigned long long v = (i < nb) ? bsum[i] : 0;
  tmp[i] = v;
  __syncthreads();
#pragma unroll
  for (int s = 1; s < 512; s <<= 1) {
    unsigned long long a = (i >= s) ? tmp[i - s] : 0;
    __syncthreads();
    tmp[i] += a;
    __syncthreads();
  }
  if (i < nb) bsum[i] = tmp[i] - v;
  if (i == 511) {
    int Ni = (int)(tmp[511] >> 32);
    int L0 = ((Ni + 255) >> 8) << 8;   // 256-aligned leaf base
    meta[0] = Ni;
    meta[1] = L0;
    meta[2] = L0 + (Nn - Ni);
  }
}

// ---------- scan pass 3: rs/cursor + slot + nodeof ----------
__global__ void k_scan3(const unsigned long long* __restrict__ ps,
                        const unsigned long long* __restrict__ bsum,
                        const int* __restrict__ meta, const int* __restrict__ deg,
                        int* __restrict__ rs, int* __restrict__ cursor,
                        int* __restrict__ slot, int* __restrict__ nodeof, int Nn) {
  int t = blockIdx.x * 256 + threadIdx.x;
  if (t >= Nn) return;
  unsigned long long p = ps[t] + bsum[blockIdx.x];
  int r  = (int)(p & 0xffffffffull);
  int si = (int)(p >> 32);
  rs[t] = r;
  cursor[t] = r;
  int sl = (deg[t] > 0) ? si : (meta[1] + (t - si));
  slot[t] = sl;
  nodeof[sl] = t;
}

// ---------- child-flag scan: pass1 per-block sums ----------
__global__ void k_cscan1(const int* __restrict__ chdeg, int* __restrict__ bs2, int Nn) {
  __shared__ int tmp[256];
  int t = blockIdx.x * 256 + threadIdx.x;
  tmp[threadIdx.x] = (t < Nn && chdeg[t] > 0) ? 1 : 0;
  __syncthreads();
#pragma unroll
  for (int s = 128; s > 0; s >>= 1) {
    if (threadIdx.x < s) tmp[threadIdx.x] += tmp[threadIdx.x + s];
    __syncthreads();
  }
  if (threadIdx.x == 0) bs2[blockIdx.x] = tmp[0];
}

// ---------- child-flag scan: pass2 (nb <= 512), total -> meta[3] ----------
__global__ void k_cscan2(int* __restrict__ bs2, int nb, int* __restrict__ meta) {
  __shared__ int tmp[512];
  int i = threadIdx.x;
  int v = (i < nb) ? bs2[i] : 0;
  tmp[i] = v;
  __syncthreads();
#pragma unroll
  for (int s = 1; s < 512; s <<= 1) {
    int a = (i >= s) ? tmp[i - s] : 0;
    __syncthreads();
    tmp[i] += a;
    __syncthreads();
  }
  if (i < nb) bs2[i] = tmp[i] - v;
  if (i == 511) meta[3] = tmp[511];   // Mc = number of distinct children
}

// ---------- child-flag scan: pass3 -> cidx / cnodes ----------
__global__ void k_cscan3(const int* __restrict__ chdeg, const int* __restrict__ bs2,
                         int* __restrict__ cidx, int* __restrict__ cnodes, int Nn) {
  __shared__ int tmp[256];
  int t = blockIdx.x * 256 + threadIdx.x;
  int v = (t < Nn && chdeg[t] > 0) ? 1 : 0;
  tmp[threadIdx.x] = v;
  __syncthreads();
#pragma unroll
  for (int s = 1; s < 256; s <<= 1) {
    int a = (threadIdx.x >= s) ? tmp[threadIdx.x - s] : 0;
    __syncthreads();
    tmp[threadIdx.x] += a;
    __syncthreads();
  }
  if (t < Nn) {
    int ci = tmp[threadIdx.x] - v + bs2[blockIdx.x];
    cidx[t] = ci;
    if (v) cnodes[ci] = t;
  }
}

// ---------- bucket edges by parent ----------
__global__ void k_fill(const int* __restrict__ parent, const int* __restrict__ child,
                       int* __restrict__ cursor, int* __restrict__ childlist, int M) {
  int e = blockIdx.x * blockDim.x + threadIdx.x;
  if (e >= M) return;
  int p = parent[e];
  int pos = atomicAdd(&cursor[p], 1);
  childlist[pos] = child[e];
}

// ---------- compact h -> bf16 for child nodes only ----------
__global__ void k_h2bf_compact(const float* __restrict__ h, const int* __restrict__ chdeg,
                               const int* __restrict__ cidx,
                               unsigned short* __restrict__ hbufc, int Nn) {
  long long t = (long long)blockIdx.x * blockDim.x + threadIdx.x;
  int n = (int)(t >> 6);
  if (n >= Nn) return;
  if (chdeg[n] == 0) return;
  int j = ((int)t & 63) * 8;
  const float4* s = (const float4*)(h + (size_t)n * 512 + j);
  size_t d = (size_t)cidx[n] * 512 + j;
  ((ushort4*)(hbufc + d))[0] = cvt4(s[0]);
  ((ushort4*)(hbufc + d))[1] = cvt4(s[1]);
}

// ---------- gather-reduce: Zp[slot]=bf16(sum h_ch | x); credb[node]=bf16(sum fc_ch) ----------
__global__ void k_reduce(const unsigned short* __restrict__ hbufc,
                         const unsigned short* __restrict__ fcc, const float* __restrict__ x,
                         const int* __restrict__ rs, const int* __restrict__ childlist,
                         const int* __restrict__ slot, const int* __restrict__ cidx,
                         unsigned short* __restrict__ Zp, unsigned short* __restrict__ credb,
                         int Nn, int M) {
  int p = blockIdx.x * 4 + (threadIdx.x >> 6);
  if (p >= Nn) return;
  int ln = threadIdx.x & 63;
  int j = ln * 8;
  int start = rs[p];
  int end = (p + 1 < Nn) ? rs[p + 1] : M;
  size_t zb = (size_t)slot[p] * 512 + j;
  if (end > start) {
    float hs[8] = {0, 0, 0, 0, 0, 0, 0, 0};
    float cs[8] = {0, 0, 0, 0, 0, 0, 0, 0};
    for (int i = start; i < end; ++i) {
      int ch = childlist[i];
      int ri = cidx[ch];                       // compact row (broadcast load)
      size_t cb = (size_t)ri * 512 + j;
      ushort8 hv = *(const ushort8*)(hbufc + cb);
      ushort8 fv = *(const ushort8*)(fcc + cb);
#pragma unroll
      for (int q = 0; q < 8; ++q) {
        hs[q] += bf2f(hv[q]);
        cs[q] += bf2f(fv[q]);
      }
    }
    float4 h0 = {hs[0], hs[1], hs[2], hs[3]}, h1 = {hs[4], hs[5], hs[6], hs[7]};
    float4 c0 = {cs[0], cs[1], cs[2], cs[3]}, c1 = {cs[4], cs[5], cs[6], cs[7]};
    ((ushort4*)(Zp + zb))[0] = cvt4(h0);
    ((ushort4*)(Zp + zb))[1] = cvt4(h1);
    size_t cr = (size_t)p * 512 + j;
    ((ushort4*)(credb + cr))[0] = cvt4(c0);
    ((ushort4*)(credb + cr))[1] = cvt4(c1);
  } else {
    const float4* s = (const float4*)(x + (size_t)p * 512 + j);
    float4 x0 = s[0], x1 = s[1];
    ((ushort4*)(Zp + zb))[0] = cvt4(x0);
    ((ushort4*)(Zp + zb))[1] = cvt4(x1);
  }
}

// ---------- f-gate GEMM (compact rows): fc = sigmoid(hbufc @ Wf^T + b) * c[node] ----------
// 256x128 tile, 8 waves, counted-vmcnt dbuf pipeline + T2 swizzle (round-9 verified loop)
__global__ __launch_bounds__(512)
void k_gemm_f(const unsigned short* __restrict__ A,
              const unsigned short* __restrict__ Bt,
              const float* __restrict__ bias, const float* __restrict__ cmat,
              const int* __restrict__ meta, const int* __restrict__ cnodes,
              unsigned short* __restrict__ C) {
  __shared__ __align__(16) unsigned short ldsA[2][256 * 32];
  __shared__ __align__(16) unsigned short ldsB[2][128 * 32];
  const int K = 512, ldc = 512;
  const int tid = threadIdx.x;
  const int wv = tid >> 6, ln = tid & 63;
  const int wr = wv >> 1, wc = wv & 1;
  int wg = xcd_swz(blockIdx.x, gridDim.x);
  int rowp = wg >> 2;
  int colp = wg & 3;
  const int row0 = rowp * 256;
  const int col0 = colp * 128;
  const int Mc = meta[3];
  if (row0 >= Mc) return;

  f32x4 acc[4][4] = {};

  auto stage = [&](int buf, int k0) {   // exactly 3 global_load_lds per thread
#pragma unroll
    for (int rep = 0; rep < 2; ++rep) {
      int cidx2 = rep * 512 + tid;
      int r  = cidx2 >> 2;
      int kc = cidx2 & 3;
      int kp = (kc ^ ((r >> 1) & 3)) * 8;
      int ga = row0 + r; if (ga > Mc - 1) ga = Mc - 1;
      const unsigned short* srcA = A + (size_t)ga * K + k0 + kp;
      __builtin_amdgcn_global_load_lds(
          (const __attribute__((address_space(1))) void*)(void*)srcA,
          (__attribute__((address_space(3))) void*)(&ldsA[buf][(size_t)cidx2 * 8]),
          16, 0, 0);
    }
    {
      int cidx2 = tid;
      int r  = cidx2 >> 2;
      int kc = cidx2 & 3;
      int kp = (kc ^ ((r >> 1) & 3)) * 8;
      const unsigned short* srcB = Bt + (size_t)(col0 + r) * K + k0 + kp;
      __builtin_amdgcn_global_load_lds(
          (const __attribute__((address_space(1))) void*)(void*)srcB,
          (__attribute__((address_space(3))) void*)(&ldsB[buf][(size_t)cidx2 * 8]),
          16, 0, 0);
    }
  };

  const int kcr = ((ln >> 4) ^ ((ln >> 1) & 3)) * 8;
  auto compute = [&](int buf) {
    bf16x8 af[4], bfr[4];
#pragma unroll
    for (int mi = 0; mi < 4; ++mi)
      af[mi] = *(const bf16x8*)(&ldsA[buf][(size_t)(wr * 64 + mi * 16 + (ln & 15)) * 32 + kcr]);
#pragma unroll
    for (int ni = 0; ni < 4; ++ni)
      bfr[ni] = *(const bf16x8*)(&ldsB[buf][(size_t)(wc * 64 + ni * 16 + (ln & 15)) * 32 + kcr]);
#pragma unroll
    for (int mi = 0; mi < 4; ++mi)
#pragma unroll
      for (int ni = 0; ni < 4; ++ni)
        acc[mi][ni] = __builtin_amdgcn_mfma_f32_16x16x32_bf16(bfr[ni], af[mi], acc[mi][ni], 0, 0, 0);
  };

  stage(0, 0);
  int cur = 0;
#pragma unroll
  for (int kt = 0; kt < 15; ++kt) {
    stage(cur ^ 1, (kt + 1) * 32);            // 6 outstanding
    asm volatile("s_waitcnt vmcnt(3)" ::: "memory");
    __builtin_amdgcn_s_barrier();
    compute(cur);
    __builtin_amdgcn_s_barrier();
    cur ^= 1;
  }
  asm volatile("s_waitcnt vmcnt(0)" ::: "memory");
  __builtin_amdgcn_s_barrier();
  compute(cur);

#pragma unroll
  for (int mi = 0; mi < 4; ++mi) {
    int gm = row0 + wr * 64 + mi * 16 + (ln & 15);
    if (gm >= Mc) continue;
    int node = cnodes[gm];
#pragma unroll
    for (int ni = 0; ni < 4; ++ni) {
      int gn = col0 + wc * 64 + ni * 16 + (ln >> 4) * 4;
      float4 bv = *(const float4*)(bias + gn);
      float4 cv = *(const float4*)(cmat + (size_t)node * ldc + gn);
      ushort4 o;
      o.x = f2bf(sigm(acc[mi][ni][0] + bv.x) * cv.x);
      o.y = f2bf(sigm(acc[mi][ni][1] + bv.y) * cv.y);
      o.z = f2bf(sigm(acc[mi][ni][2] + bv.z) * cv.z);
      o.w = f2bf(sigm(acc[mi][ni][3] + bv.w) * cv.w);
      *(ushort4*)(C + (size_t)gm * ldc + gn) = o;
    }
  }
}

// ---------- iou GEMM: 256x128, 8 waves, counted-vmcnt dbuf pipeline + T2 swizzle ----------
// (round-9 verified loop)  iou[node] = Zp @ (U|W)^T + b
__global__ __launch_bounds__(512)
void k_gemm_iou(const unsigned short* __restrict__ Zp,
                const unsigned short* __restrict__ Ub,
                const unsigned short* __restrict__ Wb,
                const float* __restrict__ bias,
                const int* __restrict__ meta,
                const int* __restrict__ nodeof,
                unsigned short* __restrict__ C) {
  __shared__ __align__(16) unsigned short ldsA[2][256 * 32];
  __shared__ __align__(16) unsigned short ldsB[2][128 * 32];
  const int K = 512, ldc = 1536;
  const int tid = threadIdx.x;
  const int wv = tid >> 6, ln = tid & 63;
  const int wr = wv >> 1, wc = wv & 1;
  int wg = xcd_swz(blockIdx.x, gridDim.x);
  int rowp = wg / 12;
  int colp = wg - rowp * 12;
  const int row0 = rowp * 256;
  const int col0 = colp * 128;

  const int Ni = meta[0], L0 = meta[1], lim2 = meta[2];
  const bool internal = row0 < L0;
  const int limit = internal ? Ni : lim2;
  if (row0 >= limit) return;
  const unsigned short* __restrict__ Bt = internal ? Ub : Wb;

  f32x4 acc[4][4] = {};

  auto stage = [&](int buf, int k0) {
#pragma unroll
    for (int rep = 0; rep < 2; ++rep) {
      int cidx2 = rep * 512 + tid;
      int r  = cidx2 >> 2;
      int kc = cidx2 & 3;
      int kp = (kc ^ ((r >> 1) & 3)) * 8;
      int ga = row0 + r; if (ga > limit - 1) ga = limit - 1;
      const unsigned short* srcA = Zp + (size_t)ga * K + k0 + kp;
      __builtin_amdgcn_global_load_lds(
          (const __attribute__((address_space(1))) void*)(void*)srcA,
          (__attribute__((address_space(3))) void*)(&ldsA[buf][(size_t)cidx2 * 8]),
          16, 0, 0);
    }
    {
      int cidx2 = tid;
      int r  = cidx2 >> 2;
      int kc = cidx2 & 3;
      int kp = (kc ^ ((r >> 1) & 3)) * 8;
      const unsigned short* srcB = Bt + (size_t)(col0 + r) * K + k0 + kp;
      __builtin_amdgcn_global_load_lds(
          (const __attribute__((address_space(1))) void*)(void*)srcB,
          (__attribute__((address_space(3))) void*)(&ldsB[buf][(size_t)cidx2 * 8]),
          16, 0, 0);
    }
  };

  const int kcr = ((ln >> 4) ^ ((ln >> 1) & 3)) * 8;
  auto compute = [&](int buf) {
    bf16x8 af[4], bfr[4];
#pragma unroll
    for (int mi = 0; mi < 4; ++mi)
      af[mi] = *(const bf16x8*)(&ldsA[buf][(size_t)(wr * 64 + mi * 16 + (ln & 15)) * 32 + kcr]);
#pragma unroll
    for (int ni = 0; ni < 4; ++ni)
      bfr[ni] = *(const bf16x8*)(&ldsB[buf][(size_t)(wc * 64 + ni * 16 + (ln & 15)) * 32 + kcr]);
#pragma unroll
    for (int mi = 0; mi < 4; ++mi)
#pragma unroll
      for (int ni = 0; ni < 4; ++ni)
        acc[mi][ni] = __builtin_amdgcn_mfma_f32_16x16x32_bf16(bfr[ni], af[mi], acc[mi][ni], 0, 0, 0);
  };

  stage(0, 0);
  int cur = 0;
#pragma unroll
  for (int kt = 0; kt < 15; ++kt) {
    stage(cur ^ 1, (kt + 1) * 32);
    asm volatile("s_waitcnt vmcnt(3)" ::: "memory");
    __builtin_amdgcn_s_barrier();
    compute(cur);
    __builtin_amdgcn_s_barrier();
    cur ^= 1;
  }
  asm volatile("s_waitcnt vmcnt(0)" ::: "memory");
  __builtin_amdgcn_s_barrier();
  compute(cur);

#pragma unroll
  for (int mi = 0; mi < 4; ++mi) {
    int m = row0 + wr * 64 + mi * 16 + (ln & 15);
    if (m >= limit) continue;
    int node = nodeof[m];
    size_t ob = (size_t)node * ldc;
#pragma unroll
    for (int ni = 0; ni < 4; ++ni) {
      int gn = col0 + wc * 64 + ni * 16 + (ln >> 4) * 4;
      float4 bv = *(const float4*)(bias + gn);
      ushort4 o;
      o.x = f2bf(acc[mi][ni][0] + bv.x);
      o.y = f2bf(acc[mi][ni][1] + bv.y);
      o.z = f2bf(acc[mi][ni][2] + bv.z);
      o.w = f2bf(acc[mi][ni][3] + bv.w);
      *(ushort4*)(C + ob + gn) = o;
    }
  }
}

// ---------- LSTM epilogue: fully coalesced (node-order iou + credb) ----------
__global__ void k_epilogue(const unsigned short* __restrict__ iou,
                           const unsigned short* __restrict__ credb,
                           const int* __restrict__ deg,
                           float* __restrict__ out, int Nn) {
  long long t = (long long)blockIdx.x * blockDim.x + threadIdx.x;
  int n = (int)(t >> 6);
  if (n >= Nn) return;
  int j = ((int)t & 63) * 8;
  size_t ib = (size_t)n * 1536;
  ushort4 iv0 = *(const ushort4*)(iou + ib + j);
  ushort4 iv1 = *(const ushort4*)(iou + ib + j + 4);
  ushort4 ov0 = *(const ushort4*)(iou + ib + 512 + j);
  ushort4 ov1 = *(const ushort4*)(iou + ib + 512 + j + 4);
  ushort4 uv0 = *(const ushort4*)(iou + ib + 1024 + j);
  ushort4 uv1 = *(const ushort4*)(iou + ib + 1024 + j + 4);

  float carr[8] = {0, 0, 0, 0, 0, 0, 0, 0};
  if (deg[n] > 0) {
    size_t cr = (size_t)n * 512 + j;
    ushort4 c0 = *(const ushort4*)(credb + cr);
    ushort4 c1 = *(const ushort4*)(credb + cr + 4);
    carr[0] = bf2f(c0.x); carr[1] = bf2f(c0.y); carr[2] = bf2f(c0.z); carr[3] = bf2f(c0.w);
    carr[4] = bf2f(c1.x); carr[5] = bf2f(c1.y); carr[6] = bf2f(c1.z); carr[7] = bf2f(c1.w);
  }

  float iarr[8] = {bf2f(iv0.x), bf2f(iv0.y), bf2f(iv0.z), bf2f(iv0.w),
                   bf2f(iv1.x), bf2f(iv1.y), bf2f(iv1.z), bf2f(iv1.w)};
  float oarr[8] = {bf2f(ov0.x), bf2f(ov0.y), bf2f(ov0.z), bf2f(ov0.w),
                   bf2f(ov1.x), bf2f(ov1.y), bf2f(ov1.z), bf2f(ov1.w)};
  float uarr[8] = {bf2f(uv0.x), bf2f(uv0.y), bf2f(uv0.z), bf2f(uv0.w),
                   bf2f(uv1.x), bf2f(uv1.y), bf2f(uv1.z), bf2f(uv1.w)};
  float hn[8], cn[8];
#pragma unroll
  for (int q = 0; q < 8; ++q) {
    float cc = sigm(iarr[q]) * tanh_f(uarr[q]) + carr[q];
    cn[q] = cc;
    hn[q] = sigm(oarr[q]) * tanh_f(cc);
  }
  size_t hb = (size_t)n * 512 + j;
  size_t cb = (size_t)Nn * 512 + hb;
  *(float4*)(out + hb)     = make_float4(hn[0], hn[1], hn[2], hn[3]);
  *(float4*)(out + hb + 4) = make_float4(hn[4], hn[5], hn[6], hn[7]);
  *(float4*)(out + cb)     = make_float4(cn[0], cn[1], cn[2], cn[3]);
  *(float4*)(out + cb + 4) = make_float4(cn[4], cn[5], cn[6], cn[7]);
}

extern "C" void kernel_launch(void* const* d_in, const int* in_sizes, int n_in,
                              void* d_out, int out_size, void* d_ws, size_t ws_size,
                              hipStream_t stream) {
  const float* x     = (const float*)d_in[0];
  const float* h     = (const float*)d_in[1];
  const float* c     = (const float*)d_in[2];
  const int* child   = (const int*)d_in[3];
  const int* parent  = (const int*)d_in[4];
  const float* W_iou = (const float*)d_in[5];
  const float* U_iou = (const float*)d_in[6];
  const float* b_iou = (const float*)d_in[7];
  const float* U_f_w = (const float*)d_in[8];
  const float* U_f_b = (const float*)d_in[9];

  const int Nn = in_sizes[0] / 512;   // 100000
  const int M  = in_sizes[3];         // 99999

  float* out = (float*)d_out;

  // ---- workspace arena (region0: fcc then iou; disjoint lifetimes) ----
  char* ws = (char*)d_ws;
  auto al = [](size_t v) { return (v + 255) & ~(size_t)255; };
  size_t sz0    = al((size_t)Nn * 1536 * 2);          // fcc (first 1/3) then iou (node-order)
  size_t offZp  = sz0;
  size_t szZp   = al((size_t)(Nn + 256) * 512 * 2);   // Zp by slot
  size_t offHb  = offZp + szZp;
  size_t szHb   = al((size_t)Nn * 512 * 2);           // hbufc (compact, <=Nn rows)
  size_t offCr  = offHb + szHb;
  size_t szCr   = al((size_t)Nn * 512 * 2);           // credb node-order
  size_t offDeg = offCr + szCr;
  size_t szN4   = al((size_t)Nn * 4);
  size_t offChd = offDeg + szN4;                      // chdeg (contiguous w/ deg for 1 memset)
  size_t offRs  = offChd + szN4;
  size_t offCur = offRs + szN4;
  size_t offSl  = offCur + szN4;
  size_t offNo  = offSl + szN4;
  size_t szNo   = al((size_t)(Nn + 256) * 4);
  size_t offCi  = offNo + szNo;                       // cidx
  size_t offCn  = offCi + szN4;                       // cnodes
  size_t offPs  = offCn + szN4;
  size_t szPs   = al((size_t)Nn * 8);
  size_t offCl  = offPs + szPs;
  size_t szCl   = al((size_t)M * 4);
  size_t offBs  = offCl + szCl;
  size_t szBs   = al(512 * 8);
  size_t offBs2 = offBs + szBs;
  size_t szBs2  = al(512 * 4);
  size_t offMt  = offBs2 + szBs2;
  size_t szMt   = 256;
  size_t offWf  = offMt + szMt;
  size_t szWf   = al(512 * 512 * 2);
  size_t offUb  = offWf + szWf;
  size_t szUw   = al((size_t)1536 * 512 * 2);
  size_t offWb  = offUb + szUw;
  size_t needed = offWb + szUw;
  if (ws_size < needed) return;

  unsigned short* fcc   = (unsigned short*)(ws);
  unsigned short* iou   = (unsigned short*)(ws);
  unsigned short* Zp    = (unsigned short*)(ws + offZp);
  unsigned short* hbufc = (unsigned short*)(ws + offHb);
  unsigned short* credb = (unsigned short*)(ws + offCr);
  int*            deg   = (int*)(ws + offDeg);
  int*            chdeg = (int*)(ws + offChd);
  int*            rs    = (int*)(ws + offRs);
  int*            cursor= (int*)(ws + offCur);
  int*            slot  = (int*)(ws + offSl);
  int*            nodeof= (int*)(ws + offNo);
  int*            cidx  = (int*)(ws + offCi);
  int*            cnodes= (int*)(ws + offCn);
  unsigned long long* ps   = (unsigned long long*)(ws + offPs);
  int*            clist = (int*)(ws + offCl);
  unsigned long long* bsum = (unsigned long long*)(ws + offBs);
  int*            bs2   = (int*)(ws + offBs2);
  int*            meta  = (int*)(ws + offMt);
  unsigned short* Wf    = (unsigned short*)(ws + offWf);
  unsigned short* Ub    = (unsigned short*)(ws + offUb);
  unsigned short* Wb    = (unsigned short*)(ws + offWb);

  hipMemsetAsync(deg, 0, 2 * szN4, stream);   // deg + chdeg

  // 1. weight conversions
  k_f2bf<<<(512 * 512 / 8 + 255) / 256, 256, 0, stream>>>(U_f_w, Wf, 512 * 512 / 8);
  k_f2bf<<<(1536 * 512 / 8 + 255) / 256, 256, 0, stream>>>(U_iou, Ub, 1536 * 512 / 8);
  k_f2bf<<<(1536 * 512 / 8 + 255) / 256, 256, 0, stream>>>(W_iou, Wb, 1536 * 512 / 8);

  // 2. CSR + partition + child-compaction build
  int nb1 = (Nn + 255) / 256;
  k_hist<<<(M + 255) / 256, 256, 0, stream>>>(parent, deg, M);
  k_hist<<<(M + 255) / 256, 256, 0, stream>>>(child, chdeg, M);
  k_scan1<<<nb1, 256, 0, stream>>>(deg, ps, bsum, Nn);
  k_scan2<<<1, 512, 0, stream>>>(bsum, nb1, meta, Nn);
  k_scan3<<<nb1, 256, 0, stream>>>(ps, bsum, meta, deg, rs, cursor, slot, nodeof, Nn);
  k_fill<<<(M + 255) / 256, 256, 0, stream>>>(parent, child, cursor, clist, M);
  k_cscan1<<<nb1, 256, 0, stream>>>(chdeg, bs2, Nn);
  k_cscan2<<<1, 512, 0, stream>>>(bs2, nb1, meta);
  k_cscan3<<<nb1, 256, 0, stream>>>(chdeg, bs2, cidx, cnodes, Nn);

  // 3. compact h -> bf16 (child rows only)
  k_h2bf_compact<<<(int)(((long long)Nn * 64 + 255) / 256), 256, 0, stream>>>(h, chdeg, cidx, hbufc, Nn);

  // 4. fcc = sigmoid(hbufc @ Wf^T + U_f_b) * c[node]   [Mc,512] bf16
  int nbyF = (Nn + 255) / 256;   // upper bound; blocks past Mc exit
  k_gemm_f<<<nbyF * 4, 512, 0, stream>>>(hbufc, Wf, U_f_b, c, meta, cnodes, fcc);

  // 5. gather-reduce -> Zp (slot-order), credb (node-order)
  k_reduce<<<(Nn + 3) / 4, 256, 0, stream>>>(hbufc, fcc, x, rs, clist, slot, cidx, Zp, credb, Nn, M);

  // 6. iou[node] = Zp @ (U_iou|W_iou)^T + b_iou  (K=512, round-9 pipeline)
  int nbyI = (Nn >> 8) + 2;
  k_gemm_iou<<<nbyI * 12, 512, 0, stream>>>(Zp, Ub, Wb, b_iou, meta, nodeof, iou);

  // 7. epilogue -> h_new, c_new (fully coalesced)
  k_epilogue<<<(int)(((long long)Nn * 64 + 255) / 256), 256, 0, stream>>>(iou, credb, deg, out, Nn);
}

// Round 14
// 683.036 us; speedup vs baseline: 1.2607x; 1.0219x over previous
//
#include <hip/hip_runtime.h>
#include <stdint.h>

typedef __bf16 bf16x8 __attribute__((ext_vector_type(8)));
typedef float f32x4 __attribute__((ext_vector_type(4)));
typedef unsigned short ushort8 __attribute__((ext_vector_type(8)));

__device__ __forceinline__ float bf2f(unsigned short u) {
  union { uint32_t i; float f; } v; v.i = ((uint32_t)u) << 16; return v.f;
}
__device__ __forceinline__ unsigned short f2bf(float f) {
  union { uint32_t i; float f; } v; v.f = f;
  uint32_t u = v.i;
  return (unsigned short)((u + 0x7fffu + ((u >> 16) & 1u)) >> 16);
}
__device__ __forceinline__ float sigm(float x) { return 1.0f / (1.0f + __expf(-x)); }
__device__ __forceinline__ float tanh_f(float x) { return 1.0f - 2.0f / (__expf(2.0f * x) + 1.0f); }

__device__ __forceinline__ ushort4 cvt4(float4 a) {
  ushort4 o; o.x = f2bf(a.x); o.y = f2bf(a.y); o.z = f2bf(a.z); o.w = f2bf(a.w); return o;
}

// bijective XCD-aware remap (m204)
__device__ __forceinline__ int xcd_swz(int bid, int nwg) {
  int q = nwg >> 3, r = nwg & 7;
  int x = bid & 7, idx = bid >> 3;
  return (x < r ? x * (q + 1) : r * (q + 1) + (x - r) * q) + idx;
}

// ---------- fp32 -> bf16 bulk convert (weights) ----------
__global__ void k_f2bf(const float* __restrict__ src, unsigned short* __restrict__ dst, long long n8) {
  long long t = (long long)blockIdx.x * blockDim.x + threadIdx.x;
  if (t >= n8) return;
  const float4* s = (const float4*)src + t * 2;
  float4 a = s[0], b = s[1];
  ((ushort4*)dst)[t * 2]     = cvt4(a);
  ((ushort4*)dst)[t * 2 + 1] = cvt4(b);
}

// ---------- merged histograms: parent->deg, child->chdeg ----------
__global__ void k_hist2(const int* __restrict__ parent, const int* __restrict__ child,
                        int* __restrict__ deg, int* __restrict__ chdeg, int M) {
  int e = blockIdx.x * blockDim.x + threadIdx.x;
  if (e >= M) return;
  atomicAdd(&deg[parent[e]], 1);
  atomicAdd(&chdeg[child[e]], 1);
}

// ---------- packed scan pass 1: 3 fields of 21 bits ----------
// f0 = deg (CSR), f1 = internal flag, f2 = is-child flag
__global__ void k_scan1(const int* __restrict__ deg, const int* __restrict__ chdeg,
                        unsigned long long* __restrict__ ps,
                        unsigned long long* __restrict__ bsum, int Nn) {
  __shared__ unsigned long long tmp[256];
  int t = blockIdx.x * 256 + threadIdx.x;
  int d  = (t < Nn) ? deg[t] : 0;
  int cf = (t < Nn && chdeg[t] > 0) ? 1 : 0;
  unsigned long long v = (unsigned long long)(unsigned)d
                       | ((d > 0) ? (1ull << 21) : 0ull)
                       | ((unsigned long long)cf << 42);
  tmp[threadIdx.x] = v;
  __syncthreads();
#pragma unroll
  for (int s = 1; s < 256; s <<= 1) {
    unsigned long long a = (threadIdx.x >= (unsigned)s) ? tmp[threadIdx.x - s] : 0;
    __syncthreads();
    tmp[threadIdx.x] += a;
    __syncthreads();
  }
  if (t < Nn) ps[t] = tmp[threadIdx.x] - v;
  if (threadIdx.x == 255) bsum[blockIdx.x] = tmp[255];
}

// ---------- scan pass 2 + meta: Ni, L0 (256-aligned), leaf-limit, Mc ----------
__global__ void k_scan2(unsigned long long* __restrict__ bsum, int nb,
                        int* __restrict__ meta, int Nn) {
  __shared__ unsigned long long tmp[512];
  int i = threadIdx.x;
  unsigned long long v = (i < nb) ? bsum[i] : 0;
  tmp[i] = v;
  __syncthreads();
#pragma unroll
  for (int s = 1; s < 512; s <<= 1) {
    unsigned long long a = (i >= s) ? tmp[i - s] : 0;
    __syncthreads();
    tmp[i] += a;
    __syncthreads();
  }
  if (i < nb) bsum[i] = tmp[i] - v;
  if (i == 511) {
    int Ni = (int)((tmp[511] >> 21) & 0x1FFFFF);
    int L0 = ((Ni + 255) >> 8) << 8;
    meta[0] = Ni;
    meta[1] = L0;
    meta[2] = L0 + (Nn - Ni);
    meta[3] = (int)((tmp[511] >> 42) & 0x1FFFFF);   // Mc
  }
}

// ---------- scan pass 3: rs/cursor + slot/nodeof + cidx/cnodes ----------
__global__ void k_scan3(const unsigned long long* __restrict__ ps,
                        const unsigned long long* __restrict__ bsum,
                        const int* __restrict__ meta, const int* __restrict__ deg,
                        const int* __restrict__ chdeg,
                        int* __restrict__ rs, int* __restrict__ cursor,
                        int* __restrict__ slot, int* __restrict__ nodeof,
                        int* __restrict__ cidx, int* __restrict__ cnodes, int Nn) {
  int t = blockIdx.x * 256 + threadIdx.x;
  if (t >= Nn) return;
  unsigned long long p = ps[t] + bsum[blockIdx.x];
  int r  = (int)(p & 0x1FFFFF);
  int si = (int)((p >> 21) & 0x1FFFFF);
  int ci = (int)((p >> 42) & 0x1FFFFF);
  rs[t] = r;
  cursor[t] = r;
  int sl = (deg[t] > 0) ? si : (meta[1] + (t - si));
  slot[t] = sl;
  nodeof[sl] = t;
  cidx[t] = ci;
  if (chdeg[t] > 0) cnodes[ci] = t;
}

// ---------- bucket edges by parent; store COMPACT child row ----------
__global__ void k_fill(const int* __restrict__ parent, const int* __restrict__ child,
                       const int* __restrict__ cidx,
                       int* __restrict__ cursor, int* __restrict__ childlist, int M) {
  int e = blockIdx.x * blockDim.x + threadIdx.x;
  if (e >= M) return;
  int p = parent[e];
  int pos = atomicAdd(&cursor[p], 1);
  childlist[pos] = cidx[child[e]];
}

// ---------- compact h -> bf16 for child nodes only ----------
__global__ void k_h2bf_compact(const float* __restrict__ h, const int* __restrict__ chdeg,
                               const int* __restrict__ cidx,
                               unsigned short* __restrict__ hbufc, int Nn) {
  long long t = (long long)blockIdx.x * blockDim.x + threadIdx.x;
  int n = (int)(t >> 6);
  if (n >= Nn) return;
  if (chdeg[n] == 0) return;
  int j = ((int)t & 63) * 8;
  const float4* s = (const float4*)(h + (size_t)n * 512 + j);
  size_t d = (size_t)cidx[n] * 512 + j;
  ((ushort4*)(hbufc + d))[0] = cvt4(s[0]);
  ((ushort4*)(hbufc + d))[1] = cvt4(s[1]);
}

// ---------- gather-reduce: childlist holds compact rows; prefetched index ----------
__global__ void k_reduce(const unsigned short* __restrict__ hbufc,
                         const unsigned short* __restrict__ fcc, const float* __restrict__ x,
                         const int* __restrict__ rs, const int* __restrict__ childlist,
                         const int* __restrict__ slot,
                         unsigned short* __restrict__ Zp, unsigned short* __restrict__ credb,
                         int Nn, int M) {
  int p = blockIdx.x * 4 + (threadIdx.x >> 6);
  if (p >= Nn) return;
  int ln = threadIdx.x & 63;
  int j = ln * 8;
  int start = rs[p];
  int end = (p + 1 < Nn) ? rs[p + 1] : M;
  size_t zb = (size_t)slot[p] * 512 + j;
  if (end > start) {
    float hs[8] = {0, 0, 0, 0, 0, 0, 0, 0};
    float cs[8] = {0, 0, 0, 0, 0, 0, 0, 0};
    int ri = childlist[start];
    for (int i = start; i < end; ++i) {
      int rin = (i + 1 < end) ? childlist[i + 1] : ri;   // prefetch next index
      size_t cb = (size_t)ri * 512 + j;
      ushort8 hv = *(const ushort8*)(hbufc + cb);
      ushort8 fv = *(const ushort8*)(fcc + cb);
#pragma unroll
      for (int q = 0; q < 8; ++q) {
        hs[q] += bf2f(hv[q]);
        cs[q] += bf2f(fv[q]);
      }
      ri = rin;
    }
    float4 h0 = {hs[0], hs[1], hs[2], hs[3]}, h1 = {hs[4], hs[5], hs[6], hs[7]};
    float4 c0 = {cs[0], cs[1], cs[2], cs[3]}, c1 = {cs[4], cs[5], cs[6], cs[7]};
    ((ushort4*)(Zp + zb))[0] = cvt4(h0);
    ((ushort4*)(Zp + zb))[1] = cvt4(h1);
    size_t cr = (size_t)p * 512 + j;
    ((ushort4*)(credb + cr))[0] = cvt4(c0);
    ((ushort4*)(credb + cr))[1] = cvt4(c1);
  } else {
    const float4* s = (const float4*)(x + (size_t)p * 512 + j);
    float4 x0 = s[0], x1 = s[1];
    ((ushort4*)(Zp + zb))[0] = cvt4(x0);
    ((ushort4*)(Zp + zb))[1] = cvt4(x1);
  }
}

// ---------- f-gate GEMM (compact rows): fc = sigmoid(hbufc @ Wf^T + b) * c[node] ----------
__global__ __launch_bounds__(512)
void k_gemm_f(const unsigned short* __restrict__ A,
              const unsigned short* __restrict__ Bt,
              const float* __restrict__ bias, const float* __restrict__ cmat,
              const int* __restrict__ meta, const int* __restrict__ cnodes,
              unsigned short* __restrict__ C) {
  __shared__ __align__(16) unsigned short ldsA[2][256 * 32];
  __shared__ __align__(16) unsigned short ldsB[2][128 * 32];
  const int K = 512, ldc = 512;
  const int tid = threadIdx.x;
  const int wv = tid >> 6, ln = tid & 63;
  const int wr = wv >> 1, wc = wv & 1;
  int wg = xcd_swz(blockIdx.x, gridDim.x);
  int rowp = wg >> 2;
  int colp = wg & 3;
  const int row0 = rowp * 256;
  const int col0 = colp * 128;
  const int Mc = meta[3];
  if (row0 >= Mc) return;

  f32x4 acc[4][4] = {};

  auto stage = [&](int buf, int k0) {
#pragma unroll
    for (int rep = 0; rep < 2; ++rep) {
      int cidx2 = rep * 512 + tid;
      int r  = cidx2 >> 2;
      int kc = cidx2 & 3;
      int kp = (kc ^ ((r >> 1) & 3)) * 8;
      int ga = row0 + r; if (ga > Mc - 1) ga = Mc - 1;
      const unsigned short* srcA = A + (size_t)ga * K + k0 + kp;
      __builtin_amdgcn_global_load_lds(
          (const __attribute__((address_space(1))) void*)(void*)srcA,
          (__attribute__((address_space(3))) void*)(&ldsA[buf][(size_t)cidx2 * 8]),
          16, 0, 0);
    }
    {
      int cidx2 = tid;
      int r  = cidx2 >> 2;
      int kc = cidx2 & 3;
      int kp = (kc ^ ((r >> 1) & 3)) * 8;
      const unsigned short* srcB = Bt + (size_t)(col0 + r) * K + k0 + kp;
      __builtin_amdgcn_global_load_lds(
          (const __attribute__((address_space(1))) void*)(void*)srcB,
          (__attribute__((address_space(3))) void*)(&ldsB[buf][(size_t)cidx2 * 8]),
          16, 0, 0);
    }
  };

  const int kcr = ((ln >> 4) ^ ((ln >> 1) & 3)) * 8;
  auto compute = [&](int buf) {
    bf16x8 af[4], bfr[4];
#pragma unroll
    for (int mi = 0; mi < 4; ++mi)
      af[mi] = *(const bf16x8*)(&ldsA[buf][(size_t)(wr * 64 + mi * 16 + (ln & 15)) * 32 + kcr]);
#pragma unroll
    for (int ni = 0; ni < 4; ++ni)
      bfr[ni] = *(const bf16x8*)(&ldsB[buf][(size_t)(wc * 64 + ni * 16 + (ln & 15)) * 32 + kcr]);
#pragma unroll
    for (int mi = 0; mi < 4; ++mi)
#pragma unroll
      for (int ni = 0; ni < 4; ++ni)
        acc[mi][ni] = __builtin_amdgcn_mfma_f32_16x16x32_bf16(bfr[ni], af[mi], acc[mi][ni], 0, 0, 0);
  };

  stage(0, 0);
  int cur = 0;
#pragma unroll
  for (int kt = 0; kt < 15; ++kt) {
    stage(cur ^ 1, (kt + 1) * 32);
    asm volatile("s_waitcnt vmcnt(3)" ::: "memory");
    __builtin_amdgcn_s_barrier();
    compute(cur);
    __builtin_amdgcn_s_barrier();
    cur ^= 1;
  }
  asm volatile("s_waitcnt vmcnt(0)" ::: "memory");
  __builtin_amdgcn_s_barrier();
  compute(cur);

#pragma unroll
  for (int mi = 0; mi < 4; ++mi) {
    int gm = row0 + wr * 64 + mi * 16 + (ln & 15);
    if (gm >= Mc) continue;
    int node = cnodes[gm];
#pragma unroll
    for (int ni = 0; ni < 4; ++ni) {
      int gn = col0 + wc * 64 + ni * 16 + (ln >> 4) * 4;
      float4 bv = *(const float4*)(bias + gn);
      float4 cv = *(const float4*)(cmat + (size_t)node * ldc + gn);
      ushort4 o;
      o.x = f2bf(sigm(acc[mi][ni][0] + bv.x) * cv.x);
      o.y = f2bf(sigm(acc[mi][ni][1] + bv.y) * cv.y);
      o.z = f2bf(sigm(acc[mi][ni][2] + bv.z) * cv.z);
      o.w = f2bf(sigm(acc[mi][ni][3] + bv.w) * cv.w);
      *(ushort4*)(C + (size_t)gm * ldc + gn) = o;
    }
  }
}

// ---------- iou GEMM: 256x128, 8 waves, counted-vmcnt dbuf pipeline + T2 swizzle ----------
__global__ __launch_bounds__(512)
void k_gemm_iou(const unsigned short* __restrict__ Zp,
                const unsigned short* __restrict__ Ub,
                const unsigned short* __restrict__ Wb,
                const float* __restrict__ bias,
                const int* __restrict__ meta,
                const int* __restrict__ nodeof,
                unsigned short* __restrict__ C) {
  __shared__ __align__(16) unsigned short ldsA[2][256 * 32];
  __shared__ __align__(16) unsigned short ldsB[2][128 * 32];
  const int K = 512, ldc = 1536;
  const int tid = threadIdx.x;
  const int wv = tid >> 6, ln = tid & 63;
  const int wr = wv >> 1, wc = wv & 1;
  int wg = xcd_swz(blockIdx.x, gridDim.x);
  int rowp = wg / 12;
  int colp = wg - rowp * 12;
  const int row0 = rowp * 256;
  const int col0 = colp * 128;

  const int Ni = meta[0], L0 = meta[1], lim2 = meta[2];
  const bool internal = row0 < L0;
  const int limit = internal ? Ni : lim2;
  if (row0 >= limit) return;
  const unsigned short* __restrict__ Bt = internal ? Ub : Wb;

  f32x4 acc[4][4] = {};

  auto stage = [&](int buf, int k0) {
#pragma unroll
    for (int rep = 0; rep < 2; ++rep) {
      int cidx2 = rep * 512 + tid;
      int r  = cidx2 >> 2;
      int kc = cidx2 & 3;
      int kp = (kc ^ ((r >> 1) & 3)) * 8;
      int ga = row0 + r; if (ga > limit - 1) ga = limit - 1;
      const unsigned short* srcA = Zp + (size_t)ga * K + k0 + kp;
      __builtin_amdgcn_global_load_lds(
          (const __attribute__((address_space(1))) void*)(void*)srcA,
          (__attribute__((address_space(3))) void*)(&ldsA[buf][(size_t)cidx2 * 8]),
          16, 0, 0);
    }
    {
      int cidx2 = tid;
      int r  = cidx2 >> 2;
      int kc = cidx2 & 3;
      int kp = (kc ^ ((r >> 1) & 3)) * 8;
      const unsigned short* srcB = Bt + (size_t)(col0 + r) * K + k0 + kp;
      __builtin_amdgcn_global_load_lds(
          (const __attribute__((address_space(1))) void*)(void*)srcB,
          (__attribute__((address_space(3))) void*)(&ldsB[buf][(size_t)cidx2 * 8]),
          16, 0, 0);
    }
  };

  const int kcr = ((ln >> 4) ^ ((ln >> 1) & 3)) * 8;
  auto compute = [&](int buf) {
    bf16x8 af[4], bfr[4];
#pragma unroll
    for (int mi = 0; mi < 4; ++mi)
      af[mi] = *(const bf16x8*)(&ldsA[buf][(size_t)(wr * 64 + mi * 16 + (ln & 15)) * 32 + kcr]);
#pragma unroll
    for (int ni = 0; ni < 4; ++ni)
      bfr[ni] = *(const bf16x8*)(&ldsB[buf][(size_t)(wc * 64 + ni * 16 + (ln & 15)) * 32 + kcr]);
#pragma unroll
    for (int mi = 0; mi < 4; ++mi)
#pragma unroll
      for (int ni = 0; ni < 4; ++ni)
        acc[mi][ni] = __builtin_amdgcn_mfma_f32_16x16x32_bf16(bfr[ni], af[mi], acc[mi][ni], 0, 0, 0);
  };

  stage(0, 0);
  int cur = 0;
#pragma unroll
  for (int kt = 0; kt < 15; ++kt) {
    stage(cur ^ 1, (kt + 1) * 32);
    asm volatile("s_waitcnt vmcnt(3)" ::: "memory");
    __builtin_amdgcn_s_barrier();
    compute(cur);
    __builtin_amdgcn_s_barrier();
    cur ^= 1;
  }
  asm volatile("s_waitcnt vmcnt(0)" ::: "memory");
  __builtin_amdgcn_s_barrier();
  compute(cur);

#pragma unroll
  for (int mi = 0; mi < 4; ++mi) {
    int m = row0 + wr * 64 + mi * 16 + (ln & 15);
    if (m >= limit) continue;
    int node = nodeof[m];
    size_t ob = (size_t)node * ldc;
#pragma unroll
    for (int ni = 0; ni < 4; ++ni) {
      int gn = col0 + wc * 64 + ni * 16 + (ln >> 4) * 4;
      float4 bv = *(const float4*)(bias + gn);
      ushort4 o;
      o.x = f2bf(acc[mi][ni][0] + bv.x);
      o.y = f2bf(acc[mi][ni][1] + bv.y);
      o.z = f2bf(acc[mi][ni][2] + bv.z);
      o.w = f2bf(acc[mi][ni][3] + bv.w);
      *(ushort4*)(C + ob + gn) = o;
    }
  }
}

// ---------- LSTM epilogue: fully coalesced (node-order iou + credb) ----------
__global__ void k_epilogue(const unsigned short* __restrict__ iou,
                           const unsigned short* __restrict__ credb,
                           const int* __restrict__ deg,
                           float* __restrict__ out, int Nn) {
  long long t = (long long)blockIdx.x * blockDim.x + threadIdx.x;
  int n = (int)(t >> 6);
  if (n >= Nn) return;
  int j = ((int)t & 63) * 8;
  size_t ib = (size_t)n * 1536;
  ushort4 iv0 = *(const ushort4*)(iou + ib + j);
  ushort4 iv1 = *(const ushort4*)(iou + ib + j + 4);
  ushort4 ov0 = *(const ushort4*)(iou + ib + 512 + j);
  ushort4 ov1 = *(const ushort4*)(iou + ib + 512 + j + 4);
  ushort4 uv0 = *(const ushort4*)(iou + ib + 1024 + j);
  ushort4 uv1 = *(const ushort4*)(iou + ib + 1024 + j + 4);

  float carr[8] = {0, 0, 0, 0, 0, 0, 0, 0};
  if (deg[n] > 0) {
    size_t cr = (size_t)n * 512 + j;
    ushort4 c0 = *(const ushort4*)(credb + cr);
    ushort4 c1 = *(const ushort4*)(credb + cr + 4);
    carr[0] = bf2f(c0.x); carr[1] = bf2f(c0.y); carr[2] = bf2f(c0.z); carr[3] = bf2f(c0.w);
    carr[4] = bf2f(c1.x); carr[5] = bf2f(c1.y); carr[6] = bf2f(c1.z); carr[7] = bf2f(c1.w);
  }

  float iarr[8] = {bf2f(iv0.x), bf2f(iv0.y), bf2f(iv0.z), bf2f(iv0.w),
                   bf2f(iv1.x), bf2f(iv1.y), bf2f(iv1.z), bf2f(iv1.w)};
  float oarr[8] = {bf2f(ov0.x), bf2f(ov0.y), bf2f(ov0.z), bf2f(ov0.w),
                   bf2f(ov1.x), bf2f(ov1.y), bf2f(ov1.z), bf2f(ov1.w)};
  float uarr[8] = {bf2f(uv0.x), bf2f(uv0.y), bf2f(uv0.z), bf2f(uv0.w),
                   bf2f(uv1.x), bf2f(uv1.y), bf2f(uv1.z), bf2f(uv1.w)};
  float hn[8], cn[8];
#pragma unroll
  for (int q = 0; q < 8; ++q) {
    float cc = sigm(iarr[q]) * tanh_f(uarr[q]) + carr[q];
    cn[q] = cc;
    hn[q] = sigm(oarr[q]) * tanh_f(cc);
  }
  size_t hb = (size_t)n * 512 + j;
  size_t cb = (size_t)Nn * 512 + hb;
  *(float4*)(out + hb)     = make_float4(hn[0], hn[1], hn[2], hn[3]);
  *(float4*)(out + hb + 4) = make_float4(hn[4], hn[5], hn[6], hn[7]);
  *(float4*)(out + cb)     = make_float4(cn[0], cn[1], cn[2], cn[3]);
  *(float4*)(out + cb + 4) = make_float4(cn[4], cn[5], cn[6], cn[7]);
}

extern "C" void kernel_launch(void* const* d_in, const int* in_sizes, int n_in,
                              void* d_out, int out_size, void* d_ws, size_t ws_size,
                              hipStream_t stream) {
  const float* x     = (const float*)d_in[0];
  const float* h     = (const float*)d_in[1];
  const float* c     = (const float*)d_in[2];
  const int* child   = (const int*)d_in[3];
  const int* parent  = (const int*)d_in[4];
  const float* W_iou = (const float*)d_in[5];
  const float* U_iou = (const float*)d_in[6];
  const float* b_iou = (const float*)d_in[7];
  const float* U_f_w = (const float*)d_in[8];
  const float* U_f_b = (const float*)d_in[9];

  const int Nn = in_sizes[0] / 512;   // 100000
  const int M  = in_sizes[3];         // 99999

  float* out = (float*)d_out;

  // ---- workspace arena (region0: fcc then iou; disjoint lifetimes) ----
  char* ws = (char*)d_ws;
  auto al = [](size_t v) { return (v + 255) & ~(size_t)255; };
  size_t sz0    = al((size_t)Nn * 1536 * 2);          // fcc (first 1/3) then iou (node-order)
  size_t offZp  = sz0;
  size_t szZp   = al((size_t)(Nn + 256) * 512 * 2);   // Zp by slot
  size_t offHb  = offZp + szZp;
  size_t szHb   = al((size_t)Nn * 512 * 2);           // hbufc (compact)
  size_t offCr  = offHb + szHb;
  size_t szCr   = al((size_t)Nn * 512 * 2);           // credb node-order
  size_t offDeg = offCr + szCr;
  size_t szN4   = al((size_t)Nn * 4);
  size_t offChd = offDeg + szN4;                      // chdeg (contiguous w/ deg)
  size_t offRs  = offChd + szN4;
  size_t offCur = offRs + szN4;
  size_t offSl  = offCur + szN4;
  size_t offNo  = offSl + szN4;
  size_t szNo   = al((size_t)(Nn + 256) * 4);
  size_t offCi  = offNo + szNo;                       // cidx
  size_t offCn  = offCi + szN4;                       // cnodes
  size_t offPs  = offCn + szN4;
  size_t szPs   = al((size_t)Nn * 8);
  size_t offCl  = offPs + szPs;
  size_t szCl   = al((size_t)M * 4);
  size_t offBs  = offCl + szCl;
  size_t szBs   = al(512 * 8);
  size_t offMt  = offBs + szBs;
  size_t szMt   = 256;
  size_t offWf  = offMt + szMt;
  size_t szWf   = al(512 * 512 * 2);
  size_t offUb  = offWf + szWf;
  size_t szUw   = al((size_t)1536 * 512 * 2);
  size_t offWb  = offUb + szUw;
  size_t needed = offWb + szUw;
  if (ws_size < needed) return;

  unsigned short* fcc   = (unsigned short*)(ws);
  unsigned short* iou   = (unsigned short*)(ws);
  unsigned short* Zp    = (unsigned short*)(ws + offZp);
  unsigned short* hbufc = (unsigned short*)(ws + offHb);
  unsigned short* credb = (unsigned short*)(ws + offCr);
  int*            deg   = (int*)(ws + offDeg);
  int*            chdeg = (int*)(ws + offChd);
  int*            rs    = (int*)(ws + offRs);
  int*            cursor= (int*)(ws + offCur);
  int*            slot  = (int*)(ws + offSl);
  int*            nodeof= (int*)(ws + offNo);
  int*            cidx  = (int*)(ws + offCi);
  int*            cnodes= (int*)(ws + offCn);
  unsigned long long* ps   = (unsigned long long*)(ws + offPs);
  int*            clist = (int*)(ws + offCl);
  unsigned long long* bsum = (unsigned long long*)(ws + offBs);
  int*            meta  = (int*)(ws + offMt);
  unsigned short* Wf    = (unsigned short*)(ws + offWf);
  unsigned short* Ub    = (unsigned short*)(ws + offUb);
  unsigned short* Wb    = (unsigned short*)(ws + offWb);

  hipMemsetAsync(deg, 0, 2 * szN4, stream);   // deg + chdeg

  // 1. weight conversions
  k_f2bf<<<(512 * 512 / 8 + 255) / 256, 256, 0, stream>>>(U_f_w, Wf, 512 * 512 / 8);
  k_f2bf<<<(1536 * 512 / 8 + 255) / 256, 256, 0, stream>>>(U_iou, Ub, 1536 * 512 / 8);
  k_f2bf<<<(1536 * 512 / 8 + 255) / 256, 256, 0, stream>>>(W_iou, Wb, 1536 * 512 / 8);

  // 2. CSR + partition + compaction build (one packed 3-field scan)
  int nb1 = (Nn + 255) / 256;
  k_hist2<<<(M + 255) / 256, 256, 0, stream>>>(parent, child, deg, chdeg, M);
  k_scan1<<<nb1, 256, 0, stream>>>(deg, chdeg, ps, bsum, Nn);
  k_scan2<<<1, 512, 0, stream>>>(bsum, nb1, meta, Nn);
  k_scan3<<<nb1, 256, 0, stream>>>(ps, bsum, meta, deg, chdeg, rs, cursor, slot, nodeof, cidx, cnodes, Nn);
  k_fill<<<(M + 255) / 256, 256, 0, stream>>>(parent, child, cidx, cursor, clist, M);

  // 3. compact h -> bf16 (child rows only)
  k_h2bf_compact<<<(int)(((long long)Nn * 64 + 255) / 256), 256, 0, stream>>>(h, chdeg, cidx, hbufc, Nn);

  // 4. fcc = sigmoid(hbufc @ Wf^T + U_f_b) * c[node]   [Mc,512] bf16
  int nbyF = (Nn + 255) / 256;   // upper bound; blocks past Mc exit
  k_gemm_f<<<nbyF * 4, 512, 0, stream>>>(hbufc, Wf, U_f_b, c, meta, cnodes, fcc);

  // 5. gather-reduce -> Zp (slot-order), credb (node-order)
  k_reduce<<<(Nn + 3) / 4, 256, 0, stream>>>(hbufc, fcc, x, rs, clist, slot, Zp, credb, Nn, M);

  // 6. iou[node] = Zp @ (U_iou|W_iou)^T + b_iou  (K=512, round-9 pipeline)
  int nbyI = (Nn >> 8) + 2;
  k_gemm_iou<<<nbyI * 12, 512, 0, stream>>>(Zp, Ub, Wb, b_iou, meta, nodeof, iou);

  // 7. epilogue -> h_new, c_new (fully coalesced)
  k_epilogue<<<(int)(((long long)Nn * 64 + 255) / 256), 256, 0, stream>>>(iou, credb, deg, out, Nn);
}